// Round 7
// baseline (558.200 us; speedup 1.0000x reference)
//
#include <hip/hip_runtime.h>
#include <hip/hip_bf16.h>

// ---------------- constants ----------------
constexpr int B_    = 32;
constexpr int S_    = 512;
constexpr int INDIM = 256;
constexpr int KCTX  = 128;
constexpr int D_    = 128;
constexpr int H_    = 4;
constexpr int L_    = 2;
constexpr int HID_  = 512;
constexpr int TOTAL_ = 11 * D_ * D_ + 8 * D_;   // 181248
constexpr int OFF_AB  = 3 * D_ * D_;            // 49152
constexpr int OFF_F1W = OFF_AB + 3 * D_;        // 49536
constexpr int OFF_F1B = OFF_F1W + 4 * D_ * D_;  // 115072
constexpr int OFF_F2W = OFF_F1B + 4 * D_;       // 115584
constexpr int OFF_F2B = OFF_F2W + 4 * D_ * D_;  // 181120

typedef __attribute__((ext_vector_type(8))) short short8;
typedef __attribute__((ext_vector_type(4))) short short4v;
typedef __attribute__((ext_vector_type(2))) short short2v;
typedef __attribute__((ext_vector_type(4))) float f32x4;

#define MFMA16 __builtin_amdgcn_mfma_f32_16x16x32_bf16

__device__ __forceinline__ short f2bf(float f) {
  __hip_bfloat16 h = __float2bfloat16(f);
  return __builtin_bit_cast(short, h);
}
__device__ __forceinline__ float bf2f(short s) {
  __hip_bfloat16 h = __builtin_bit_cast(__hip_bfloat16, s);
  return __bfloat162float(h);
}
struct bfpair { short hi, lo; };
__device__ __forceinline__ bfpair split2p(float x) {
  bfpair p;
  p.hi = f2bf(x);
  p.lo = f2bf(x - bf2f(p.hi));
  return p;
}

// Fragment-tiled (FT) layout: matrix (rows, K) stored as 16x8 tiles:
// addr(row,k) = ((row>>4)*(K>>3) + (k>>3))*128 + (row&15)*8 + (k&7)
__device__ __forceinline__ long ftaddr(int row, int k, int K) {
  return ((long)(row >> 4) * (K >> 3) + (k >> 3)) * 128 + (row & 15) * 8 + (k & 7);
}

// ---------------- fp32 row-major -> FT split planes ----------------
__global__ void k_cvtft(const float* __restrict__ in, short* __restrict__ oh,
                        short* __restrict__ ol, int ktShift, int n8) {
  int t = blockIdx.x * 256 + threadIdx.x;
  if (t >= n8) return;
  int kt = 1 << ktShift;              // K/8
  int row = t >> ktShift;
  int kc = t & (kt - 1);
  const float* p = in + ((long)row << (ktShift + 3)) + kc * 8;
  float4 v0 = *(const float4*)p;
  float4 v1 = *(const float4*)(p + 4);
  short8 h8, l8;
  bfpair q;
  q = split2p(v0.x); h8[0] = q.hi; l8[0] = q.lo;
  q = split2p(v0.y); h8[1] = q.hi; l8[1] = q.lo;
  q = split2p(v0.z); h8[2] = q.hi; l8[2] = q.lo;
  q = split2p(v0.w); h8[3] = q.hi; l8[3] = q.lo;
  q = split2p(v1.x); h8[4] = q.hi; l8[4] = q.lo;
  q = split2p(v1.y); h8[5] = q.hi; l8[5] = q.lo;
  q = split2p(v1.z); h8[6] = q.hi; l8[6] = q.lo;
  q = split2p(v1.w); h8[7] = q.hi; l8[7] = q.lo;
  long o = ((long)(row >> 4) * kt + kc) * 128 + (row & 15) * 8;
  *(short8*)(oh + o) = h8;
  *(short8*)(ol + o) = l8;
}

// ---------------- hid = relu(ctx @ hfc1_w^T + b), FT planes (rows=32,K=512) --
__global__ __launch_bounds__(512) void k_hid(const float* __restrict__ cvec,
                                             const float* __restrict__ w,
                                             const float* __restrict__ bias,
                                             short* __restrict__ hh,
                                             short* __restrict__ hl) {
  int lb = blockIdx.x;            // l*32 + b
  int b  = lb & 31;
  int j  = threadIdx.x;
  __shared__ float cs[KCTX];
  if (j < KCTX) cs[j] = cvec[b * KCTX + j];
  __syncthreads();
  int l = lb >> 5;
  const float* wr = w + (long)(l * HID_ + j) * KCTX;
  float s = bias[l * HID_ + j];
  #pragma unroll
  for (int c = 0; c < KCTX; c += 4) {
    float4 cv = *(const float4*)(cs + c);
    float4 wv = *(const float4*)(wr + c);
    s += cv.x * wv.x + cv.y * wv.y + cv.z * wv.z + cv.w * wv.w;
  }
  s = fmaxf(s, 0.f);
  bfpair p = split2p(s);
  long o = (long)l * 32 * HID_ + ((long)(b >> 4) * 64 + (j >> 3)) * 128 + (b & 15) * 8 + (j & 7);
  hh[o] = p.hi;
  hl[o] = p.lo;
}

// ---------------- k_flat: flat = hid @ hfc2_w^T + b (no-LDS, reg pipeline) ---
__device__ __forceinline__ void store_flat(int b, int trow, float v,
    short* __restrict__ awh, short* __restrict__ awl,
    short* __restrict__ f1h, short* __restrict__ f1l,
    short* __restrict__ f2h, short* __restrict__ f2l,
    float* __restrict__ ab, float* __restrict__ f1b, float* __restrict__ f2b) {
  if (trow < OFF_AB) {
    int e = trow >> 7, d = trow & 127;
    long a = (long)b * 49152 + ftaddr(e, d, 128);
    bfpair p = split2p(v); awh[a] = p.hi; awl[a] = p.lo;
  } else if (trow < OFF_F1W) {
    ab[b * 384 + trow - OFF_AB] = v;
  } else if (trow < OFF_F1B) {
    int i = trow - OFF_F1W; int f = i >> 7, d = i & 127;
    long a = (long)b * 65536 + ftaddr(f, d, 128);
    bfpair p = split2p(v); f1h[a] = p.hi; f1l[a] = p.lo;
  } else if (trow < OFF_F2W) {
    f1b[b * 512 + trow - OFF_F1B] = v;
  } else if (trow < OFF_F2B) {
    int i = trow - OFF_F2W; int dd = i >> 9, f = i & 511;
    long a = (long)b * 65536 + ftaddr(dd, f, 512);
    bfpair p = split2p(v); f2h[a] = p.hi; f2l[a] = p.lo;
  } else {
    f2b[b * 128 + trow - OFF_F2B] = v;
  }
}

__global__ __launch_bounds__(256) void k_flat(
    const short* __restrict__ hidh, const short* __restrict__ hidl,  // FT(32,512)
    const float* __restrict__ W, const float* __restrict__ bias,
    short* __restrict__ awh, short* __restrict__ awl,
    short* __restrict__ f1h, short* __restrict__ f1l,
    short* __restrict__ f2h, short* __restrict__ f2l,
    float* __restrict__ ab, float* __restrict__ f1b, float* __restrict__ f2b) {
  const int tid = threadIdx.x, wave = tid >> 6, lane = tid & 63;
  const int r = lane & 15, g = lane >> 4;
  const int nb0 = blockIdx.x * 64;
  const int wrow = nb0 + wave * 16 + r;
  // each lane streams its own W fragment directly: rows wrow, cols g*8..
  const float* wp = W + (long)wrow * HID_ + g * 8;
  const short* pAh = hidh + g * 128 + r * 8;
  const short* pAl = hidl + g * 128 + r * 8;
  f32x4 acc0 = {0, 0, 0, 0}, acc1 = {0, 0, 0, 0};
  // 2-deep register prefetch, no LDS, no barriers
  float4 w0 = *(const float4*)(wp);
  float4 w1 = *(const float4*)(wp + 4);
  short8 ah0 = *(const short8*)(pAh);
  short8 ah1 = *(const short8*)(pAh + 8192);
  short8 al0 = *(const short8*)(pAl);
  short8 al1 = *(const short8*)(pAl + 8192);
  #pragma unroll
  for (int kk = 0; kk < 16; ++kk) {
    float4 cw0 = w0, cw1 = w1;
    short8 ch0 = ah0, ch1 = ah1, cl0 = al0, cl1 = al1;
    if (kk < 15) {
      long wo = (long)(kk + 1) * 32;
      w0 = *(const float4*)(wp + wo);
      w1 = *(const float4*)(wp + wo + 4);
      long ao = (long)(kk + 1) * 512;
      ah0 = *(const short8*)(pAh + ao);
      ah1 = *(const short8*)(pAh + 8192 + ao);
      al0 = *(const short8*)(pAl + ao);
      al1 = *(const short8*)(pAl + 8192 + ao);
    }
    short8 wh, wl; bfpair q;
    q = split2p(cw0.x); wh[0] = q.hi; wl[0] = q.lo;
    q = split2p(cw0.y); wh[1] = q.hi; wl[1] = q.lo;
    q = split2p(cw0.z); wh[2] = q.hi; wl[2] = q.lo;
    q = split2p(cw0.w); wh[3] = q.hi; wl[3] = q.lo;
    q = split2p(cw1.x); wh[4] = q.hi; wl[4] = q.lo;
    q = split2p(cw1.y); wh[5] = q.hi; wl[5] = q.lo;
    q = split2p(cw1.z); wh[6] = q.hi; wl[6] = q.lo;
    q = split2p(cw1.w); wh[7] = q.hi; wl[7] = q.lo;
    acc0 = MFMA16(ch0, wl, acc0, 0, 0, 0);
    acc0 = MFMA16(cl0, wh, acc0, 0, 0, 0);
    acc0 = MFMA16(ch0, wh, acc0, 0, 0, 0);
    acc1 = MFMA16(ch1, wl, acc1, 0, 0, 0);
    acc1 = MFMA16(cl1, wh, acc1, 0, 0, 0);
    acc1 = MFMA16(ch1, wh, acc1, 0, 0, 0);
  }
  float bv = bias[wrow];
  #pragma unroll
  for (int reg = 0; reg < 4; ++reg) {
    store_flat(g * 4 + reg, wrow, acc0[reg] + bv, awh, awl, f1h, f1l, f2h, f2l, ab, f1b, f2b);
    store_flat(g * 4 + reg + 16, wrow, acc1[reg] + bv, awh, awl, f1h, f1l, f2h, f2l, ab, f1b, f2b);
  }
}

// ---------------- generic batched split-MFMA GEMM, FT operands ----------------
// grid: (x = m-tile(64), y = n-tile(128), z = b).
// EPI: 0 = FT split planes out (p0,p1; pitch N); 1 = in_proj (+pe, p0=h_f f32,
//      p1/p2 FT planes); 4 = fused residual+LN (p0=h_f rw, p1/p2 FT planes,
//      lng/lnb/lnal); 5 = qkv routing (p0/p1 = qk planes, p2/p3 = vt planes).
template <int K, int EPI, bool RELU>
__global__ __launch_bounds__(256) void k_gemm(
    const short* __restrict__ Ah, const short* __restrict__ Al, long sA,
    const short* __restrict__ Wh, const short* __restrict__ Wl, long sW,
    const float* __restrict__ biasP, long sB,
    void* __restrict__ p0, void* __restrict__ p1,
    void* __restrict__ p2, void* __restrict__ p3,
    const float* __restrict__ pe, int N,
    const float* __restrict__ lng, const float* __restrict__ lnb,
    const float* __restrict__ lnal) {
  extern __shared__ char smem_dyn[];
  const int tid = threadIdx.x, wave = tid >> 6, lane = tid & 63;
  const int r = lane & 15, g = lane >> 4;
  const int b = blockIdx.z;
  const int m0 = blockIdx.x * 64 + (wave & 1) * 32;
  const int n0 = blockIdx.y * 128 + (wave >> 1) * 64;
  const long KT = (long)K * 16;
  const short* pAh = Ah + (long)b * sA + (m0 >> 4) * KT + g * 128 + r * 8;
  const short* pAl = Al + (long)b * sA + (m0 >> 4) * KT + g * 128 + r * 8;
  const short* pWh = Wh + (long)b * sW + (n0 >> 4) * KT + g * 128 + r * 8;
  const short* pWl = Wl + (long)b * sW + (n0 >> 4) * KT + g * 128 + r * 8;
  f32x4 acc[2][4] = {{{0,0,0,0},{0,0,0,0},{0,0,0,0},{0,0,0,0}},
                     {{0,0,0,0},{0,0,0,0},{0,0,0,0},{0,0,0,0}}};
  for (int kk = 0; kk < K / 32; ++kk) {
    long ko = (long)kk * 512;
    short8 a0h = *(const short8*)(pAh + ko);
    short8 a1h = *(const short8*)(pAh + KT + ko);
    short8 a0l = *(const short8*)(pAl + ko);
    short8 a1l = *(const short8*)(pAl + KT + ko);
    #pragma unroll
    for (int ns = 0; ns < 4; ++ns) {
      short8 wh = *(const short8*)(pWh + ns * KT + ko);
      short8 wl = *(const short8*)(pWl + ns * KT + ko);
      acc[0][ns] = MFMA16(a0h, wl, acc[0][ns], 0, 0, 0);
      acc[0][ns] = MFMA16(a0l, wh, acc[0][ns], 0, 0, 0);
      acc[0][ns] = MFMA16(a0h, wh, acc[0][ns], 0, 0, 0);
      acc[1][ns] = MFMA16(a1h, wl, acc[1][ns], 0, 0, 0);
      acc[1][ns] = MFMA16(a1l, wh, acc[1][ns], 0, 0, 0);
      acc[1][ns] = MFMA16(a1h, wh, acc[1][ns], 0, 0, 0);
    }
  }
  #pragma unroll
  for (int ms = 0; ms < 2; ++ms) {
    #pragma unroll
    for (int ns = 0; ns < 4; ++ns) {
      int ccol = n0 + ns * 16 + r;
      float bv = biasP[(long)b * sB + ccol];
      #pragma unroll
      for (int reg = 0; reg < 4; ++reg) {
        int crow = m0 + ms * 16 + g * 4 + reg;
        float v = acc[ms][ns][reg] + bv;
        if constexpr (RELU) v = fmaxf(v, 0.f);
        if constexpr (EPI == 0) {
          long o = (long)b * 512 * N + (long)(crow >> 4) * (N * 16)
                 + (long)(ccol >> 3) * 128 + (crow & 15) * 8 + (ccol & 7);
          bfpair sp = split2p(v);
          ((short*)p0)[o] = sp.hi;
          ((short*)p1)[o] = sp.lo;
        } else if constexpr (EPI == 1) {
          v += pe[crow * D_ + ccol];
          ((float*)p0)[((long)b * S_ + crow) * D_ + ccol] = v;
          long o = (long)b * 65536 + (long)(crow >> 4) * 2048
                 + (ccol >> 3) * 128 + (crow & 15) * 8 + (ccol & 7);
          bfpair sp = split2p(v);
          ((short*)p1)[o] = sp.hi;
          ((short*)p2)[o] = sp.lo;
        } else if constexpr (EPI == 4) {
          float* tile = (float*)smem_dyn;
          int trow2 = (wave & 1) * 32 + ms * 16 + g * 4 + reg;
          int tcol = (wave >> 1) * 64 + ns * 16 + r;
          tile[trow2 * 136 + tcol] = v;
        } else {  // EPI == 5
          bfpair sp = split2p(v);
          if (n0 < 256) {
            long o = (long)b * 131072 + (long)(crow >> 4) * 4096
                   + (ccol >> 3) * 128 + (crow & 15) * 8 + (ccol & 7);
            ((short*)p0)[o] = sp.hi;
            ((short*)p1)[o] = sp.lo;
          } else {
            int c2 = ccol - 256; int hd = c2 >> 5, dd = c2 & 31;
            long o = (long)(b * 4 + hd) * 16384 + (dd >> 4) * 8192
                   + (crow >> 3) * 128 + (dd & 15) * 8 + (crow & 7);
            ((short*)p2)[o] = sp.hi;
            ((short*)p3)[o] = sp.lo;
          }
        }
      }
    }
  }
  if constexpr (EPI == 4) {
    float* tile = (float*)smem_dyn;
    __syncthreads();
    int row = tid >> 2, q = tid & 3;
    int brow = blockIdx.x * 64 + row;
    float a = lnal[0];
    float* hf = (float*)p0;
    float* hrow = hf + ((long)b * S_ + brow) * D_ + q * 32;
    float tv[32];
    float s = 0.f, ss = 0.f;
    #pragma unroll
    for (int i = 0; i < 32; i += 4) {
      float4 hv = *(const float4*)(hrow + i);
      float4 yv = *(const float4*)&tile[row * 136 + q * 32 + i];
      float t0 = hv.x + a * yv.x, t1 = hv.y + a * yv.y;
      float t2 = hv.z + a * yv.z, t3 = hv.w + a * yv.w;
      tv[i] = t0; tv[i+1] = t1; tv[i+2] = t2; tv[i+3] = t3;
      s += t0 + t1 + t2 + t3;
      ss += t0*t0 + t1*t1 + t2*t2 + t3*t3;
    }
    s  += __shfl_xor(s, 1);  s  += __shfl_xor(s, 2);
    ss += __shfl_xor(ss, 1); ss += __shfl_xor(ss, 2);
    float mu = s * (1.f / 128.f);
    float varv = ss * (1.f / 128.f) - mu * mu;
    float inv = rsqrtf(varv + 1e-5f);
    short* ph = (short*)p1; short* pl = (short*)p2;
    long fb = (long)b * 65536 + (long)(brow >> 4) * 2048 + (brow & 15) * 8;
    #pragma unroll
    for (int j = 0; j < 4; ++j) {
      short8 hv8, lv8;
      #pragma unroll
      for (int e = 0; e < 8; e += 4) {
        int i = j * 8 + e;
        int c = q * 32 + i;
        float4 gv = *(const float4*)(lng + c);
        float4 bb = *(const float4*)(lnb + c);
        float4 o4;
        o4.x = (tv[i]   - mu) * inv * gv.x + bb.x;
        o4.y = (tv[i+1] - mu) * inv * gv.y + bb.y;
        o4.z = (tv[i+2] - mu) * inv * gv.z + bb.z;
        o4.w = (tv[i+3] - mu) * inv * gv.w + bb.w;
        *(float4*)(hrow + i) = o4;
        bfpair q0 = split2p(o4.x); hv8[e]   = q0.hi; lv8[e]   = q0.lo;
        bfpair q1 = split2p(o4.y); hv8[e+1] = q1.hi; lv8[e+1] = q1.lo;
        bfpair q2 = split2p(o4.z); hv8[e+2] = q2.hi; lv8[e+2] = q2.lo;
        bfpair q3 = split2p(o4.w); hv8[e+3] = q3.hi; lv8[e+3] = q3.lo;
      }
      long o = fb + (q * 4 + j) * 128;
      *(short8*)(ph + o) = hv8;
      *(short8*)(pl + o) = lv8;
    }
  }
}

// ---------------- attention: 16 q-rows/block, 2 cooperating waves ------------
__global__ __launch_bounds__(128) void k_attn(const short* __restrict__ qkh,
                                              const short* __restrict__ qkl,
                                              const short* __restrict__ vth,
                                              const short* __restrict__ vtl,
                                              short* __restrict__ ch,
                                              short* __restrict__ cl) {
  __shared__ __align__(16) float scr[16][516];   // 33 KB
  __shared__ __align__(16) float obuf[16][34];   // 2.2 KB
  const int tid = threadIdx.x, wave = tid >> 6, lane = tid & 63;
  const int r = lane & 15, g = lane >> 4;
  const int b = blockIdx.z, hh = blockIdx.y;
  const int m0 = blockIdx.x * 16;
  const long qb = (long)b * 131072;
  const long qoff = qb + (long)(m0 >> 4) * 4096 + (hh * 4 + g) * 128 + r * 8;
  short8 qh = *(const short8*)(qkh + qoff);
  short8 ql = *(const short8*)(qkl + qoff);
  const float sc = 0.17677669529663687f;  // 1/sqrt(32)
  // QK: wave w handles k-range [w*256, w*256+256)
  for (int n0 = wave * 256; n0 < wave * 256 + 256; n0 += 16) {
    long koff = qb + (long)(n0 >> 4) * 4096 + (16 + hh * 4 + g) * 128 + r * 8;
    short8 kh = *(const short8*)(qkh + koff);
    short8 kl = *(const short8*)(qkl + koff);
    f32x4 s = {0, 0, 0, 0};
    s = MFMA16(qh, kl, s, 0, 0, 0);
    s = MFMA16(ql, kh, s, 0, 0, 0);
    s = MFMA16(qh, kh, s, 0, 0, 0);
    #pragma unroll
    for (int reg = 0; reg < 4; ++reg)
      scr[g * 4 + reg][n0 + r] = s[reg] * sc;
  }
  __syncthreads();
  // softmax: wave w handles rows [w*8, w*8+8)
  for (int row = wave * 8; row < wave * 8 + 8; ++row) {
    float v[8];
    #pragma unroll
    for (int i = 0; i < 8; ++i) v[i] = scr[row][lane + i * 64];
    float m = v[0];
    #pragma unroll
    for (int i = 1; i < 8; ++i) m = fmaxf(m, v[i]);
    #pragma unroll
    for (int o = 32; o > 0; o >>= 1) m = fmaxf(m, __shfl_xor(m, o));
    float ssum = 0.f;
    #pragma unroll
    for (int i = 0; i < 8; ++i) { v[i] = __expf(v[i] - m); ssum += v[i]; }
    #pragma unroll
    for (int o = 32; o > 0; o >>= 1) ssum += __shfl_xor(ssum, o);
    float inv = 1.f / ssum;
    #pragma unroll
    for (int i = 0; i < 8; ++i) scr[row][lane + i * 64] = v[i] * inv;
  }
  __syncthreads();
  // PV: wave w handles kt range [w*8, w*8+8); partials combined via obuf
  f32x4 o0 = {0, 0, 0, 0}, o1 = {0, 0, 0, 0};
  const long vb = (long)(b * 4 + hh) * 16384;
  for (int kt = wave * 8; kt < wave * 8 + 8; ++kt) {
    float4 pv0 = *(const float4*)&scr[r][kt * 32 + g * 8];
    float4 pv1 = *(const float4*)&scr[r][kt * 32 + g * 8 + 4];
    short8 pah, pal;
    bfpair p;
    p = split2p(pv0.x); pah[0] = p.hi; pal[0] = p.lo;
    p = split2p(pv0.y); pah[1] = p.hi; pal[1] = p.lo;
    p = split2p(pv0.z); pah[2] = p.hi; pal[2] = p.lo;
    p = split2p(pv0.w); pah[3] = p.hi; pal[3] = p.lo;
    p = split2p(pv1.x); pah[4] = p.hi; pal[4] = p.lo;
    p = split2p(pv1.y); pah[5] = p.hi; pal[5] = p.lo;
    p = split2p(pv1.z); pah[6] = p.hi; pal[6] = p.lo;
    p = split2p(pv1.w); pah[7] = p.hi; pal[7] = p.lo;
    long vo = vb + (long)(kt * 4 + g) * 128 + r * 8;
    short8 vh0 = *(const short8*)(vth + vo);
    short8 vh1 = *(const short8*)(vth + vo + 8192);
    short8 vl0 = *(const short8*)(vtl + vo);
    short8 vl1 = *(const short8*)(vtl + vo + 8192);
    o0 = MFMA16(pah, vl0, o0, 0, 0, 0);
    o0 = MFMA16(pal, vh0, o0, 0, 0, 0);
    o0 = MFMA16(pah, vh0, o0, 0, 0, 0);
    o1 = MFMA16(pah, vl1, o1, 0, 0, 0);
    o1 = MFMA16(pal, vh1, o1, 0, 0, 0);
    o1 = MFMA16(pah, vh1, o1, 0, 0, 0);
  }
  if (wave == 1) {
    #pragma unroll
    for (int reg = 0; reg < 4; ++reg) {
      obuf[g * 4 + reg][r] = o0[reg];
      obuf[g * 4 + reg][17 + r] = o1[reg];
    }
  }
  __syncthreads();
  if (wave == 0) {
    #pragma unroll
    for (int reg = 0; reg < 4; ++reg) {
      float a0 = o0[reg] + obuf[g * 4 + reg][r];
      float a1 = o1[reg] + obuf[g * 4 + reg][17 + r];
      int srow = m0 + g * 4 + reg;
      int col0 = hh * 32 + r;
      long o = (long)b * 65536 + (long)(srow >> 4) * 2048
             + (col0 >> 3) * 128 + (srow & 15) * 8 + (col0 & 7);
      bfpair sp0 = split2p(a0);
      ch[o] = sp0.hi; cl[o] = sp0.lo;
      long o2 = o + 2 * 128;
      bfpair sp1 = split2p(a1);
      ch[o2] = sp1.hi; cl[o2] = sp1.lo;
    }
  }
}

// ---------------- head ----------------
__global__ __launch_bounds__(64) void k_head(const float* __restrict__ h,
                                             const float* __restrict__ hw,
                                             const float* __restrict__ hb,
                                             float* __restrict__ out) {
  int b = blockIdx.x, lane = threadIdx.x;
  const float* hr = h + ((long)b * S_ + (S_ - 1)) * D_;
  float v = hr[lane] * hw[lane] + hr[lane + 64] * hw[lane + 64];
  #pragma unroll
  for (int o = 32; o > 0; o >>= 1) v += __shfl_xor(v, o);
  if (lane == 0) out[b] = v + hb[0];
}

// ---------------- host ----------------
extern "C" void kernel_launch(void* const* d_in, const int* in_sizes, int n_in,
                              void* d_out, int out_size, void* d_ws, size_t ws_size,
                              hipStream_t stream) {
  const float* x    = (const float*)d_in[0];
  const float* cvec = (const float*)d_in[1];
  const float* ipw  = (const float*)d_in[2];
  const float* ipb  = (const float*)d_in[3];
  const float* pe   = (const float*)d_in[4];
  const float* h1w  = (const float*)d_in[5];
  const float* h1b  = (const float*)d_in[6];
  const float* h2w  = (const float*)d_in[7];
  const float* h2b  = (const float*)d_in[8];
  const float* opw  = (const float*)d_in[9];
  const float* opb  = (const float*)d_in[10];
  const float* ln1g = (const float*)d_in[11];
  const float* ln1b = (const float*)d_in[12];
  const float* ln2g = (const float*)d_in[13];
  const float* ln2b = (const float*)d_in[14];
  const float* a1   = (const float*)d_in[15];
  const float* a2   = (const float*)d_in[16];
  const float* hw   = (const float*)d_in[17];
  const float* hb   = (const float*)d_in[18];
  float* out = (float*)d_out;

  char* ws = (char*)d_ws;
  size_t off = 0;
  auto alloc = [&](size_t n) { void* p = ws + off; off = (off + n + 255) & ~(size_t)255; return p; };

  short* ff1h  = (short*)alloc((size_t)B_ * S_ * 512 * 2);   // aliases xFh
  short* ff1l  = (short*)alloc((size_t)B_ * S_ * 512 * 2);
  short* xFh   = ff1h;    // x planes dead before ff1 written
  short* xFl   = ff1l;
  float* h_f   = (float*)alloc((size_t)B_ * S_ * D_ * 4);
  short* hFh   = (short*)alloc((size_t)B_ * S_ * D_ * 2);
  short* hFl   = (short*)alloc((size_t)B_ * S_ * D_ * 2);
  short* hidFh = (short*)alloc((size_t)L_ * 32 * HID_ * 2);
  short* hidFl = (short*)alloc((size_t)L_ * 32 * HID_ * 2);
  short* awFh  = (short*)alloc((size_t)B_ * 49152 * 2);
  short* awFl  = (short*)alloc((size_t)B_ * 49152 * 2);
  short* f1wFh = (short*)alloc((size_t)B_ * 65536 * 2);
  short* f1wFl = (short*)alloc((size_t)B_ * 65536 * 2);
  short* f2wFh = (short*)alloc((size_t)B_ * 65536 * 2);
  short* f2wFl = (short*)alloc((size_t)B_ * 65536 * 2);
  float* abF   = (float*)alloc((size_t)B_ * 384 * 4);
  float* f1bF  = (float*)alloc((size_t)B_ * 512 * 4);
  float* f2bF  = (float*)alloc((size_t)B_ * 128 * 4);
  short* qkFh  = (short*)alloc((size_t)B_ * S_ * 256 * 2);
  short* qkFl  = (short*)alloc((size_t)B_ * S_ * 256 * 2);
  short* vtFh  = (short*)alloc((size_t)B_ * H_ * 32 * S_ * 2);
  short* vtFl  = (short*)alloc((size_t)B_ * H_ * 32 * S_ * 2);
  short* cxFh  = (short*)alloc((size_t)B_ * S_ * D_ * 2);
  short* cxFl  = (short*)alloc((size_t)B_ * S_ * D_ * 2);
  short* ipwFh = (short*)alloc((size_t)D_ * INDIM * 2);
  short* ipwFl = (short*)alloc((size_t)D_ * INDIM * 2);
  short* opwFh = (short*)alloc((size_t)L_ * D_ * D_ * 2);
  short* opwFl = (short*)alloc((size_t)L_ * D_ * D_ * 2);

  k_cvtft<<<(B_ * S_ * INDIM / 8 + 255) / 256, 256, 0, stream>>>(x, xFh, xFl, 5, B_ * S_ * INDIM / 8);
  k_cvtft<<<16, 256, 0, stream>>>(ipw, ipwFh, ipwFl, 5, D_ * INDIM / 8);
  k_cvtft<<<16, 256, 0, stream>>>(opw, opwFh, opwFl, 4, L_ * D_ * D_ / 8);

  k_hid<<<L_ * 32, 512, 0, stream>>>(cvec, h1w, h1b, hidFh, hidFl);

  // h = x @ in_proj^T + b + pe
  k_gemm<INDIM, 1, false><<<dim3(8, 1, B_), 256, 0, stream>>>(
      xFh, xFl, (long)S_ * INDIM, ipwFh, ipwFl, 0, ipb, 0,
      h_f, hFh, hFl, nullptr, pe, 128, nullptr, nullptr, nullptr);

  constexpr size_t LN_LDS = 64 * 136 * 4;
  for (int l = 0; l < L_; ++l) {
    k_flat<<<TOTAL_ / 64, 256, 0, stream>>>(
        hidFh + (long)l * 32 * HID_, hidFl + (long)l * 32 * HID_,
        h2w + (long)l * TOTAL_ * HID_, h2b + (long)l * TOTAL_,
        awFh, awFl, f1wFh, f1wFl, f2wFh, f2wFl, abF, f1bF, f2bF);
    // qkv fused (N=384): blocks y=0,1 -> qk planes; y=2 -> vt planes
    k_gemm<D_, 5, false><<<dim3(8, 3, B_), 256, 0, stream>>>(
        hFh, hFl, (long)S_ * D_, awFh, awFl, 49152, abF, 384,
        qkFh, qkFl, vtFh, vtFl, nullptr, 256, nullptr, nullptr, nullptr);
    k_attn<<<dim3(S_ / 16, H_, B_), 128, 0, stream>>>(qkFh, qkFl, vtFh, vtFl, cxFh, cxFl);
    // out_proj + residual + LN1 fused
    k_gemm<D_, 4, false><<<dim3(8, 1, B_), 256, LN_LDS, stream>>>(
        cxFh, cxFl, (long)S_ * D_, opwFh + l * 16384, opwFl + l * 16384, 0,
        opb + l * D_, 0, h_f, hFh, hFl, nullptr, nullptr, 128,
        ln1g + l * D_, ln1b + l * D_, a1 + l);
    // ffn1 (relu) -> ff1 FT(512,512)
    k_gemm<D_, 0, true><<<dim3(8, 4, B_), 256, 0, stream>>>(
        hFh, hFl, (long)S_ * D_, f1wFh, f1wFl, 65536, f1bF, 512,
        ff1h, ff1l, nullptr, nullptr, nullptr, 512, nullptr, nullptr, nullptr);
    // ffn2 + residual + LN2 fused
    k_gemm<512, 4, false><<<dim3(8, 1, B_), 256, LN_LDS, stream>>>(
        ff1h, ff1l, (long)S_ * 512, f2wFh, f2wFl, 65536, f2bF, 128,
        h_f, hFh, hFl, nullptr, nullptr, 128,
        ln2g + l * D_, ln2b + l * D_, a2 + l);
  }
  k_head<<<B_, 64, 0, stream>>>(h_f, hw, hb, out);
}

// Round 8
// 506.147 us; speedup vs baseline: 1.1028x; 1.1028x over previous
//
#include <hip/hip_runtime.h>
#include <hip/hip_bf16.h>

// ---------------- constants ----------------
constexpr int B_    = 32;
constexpr int S_    = 512;
constexpr int INDIM = 256;
constexpr int KCTX  = 128;
constexpr int D_    = 128;
constexpr int H_    = 4;
constexpr int L_    = 2;
constexpr int HID_  = 512;
constexpr int TOTAL_ = 11 * D_ * D_ + 8 * D_;   // 181248
constexpr int OFF_AB  = 3 * D_ * D_;            // 49152
constexpr int OFF_F1W = OFF_AB + 3 * D_;        // 49536
constexpr int OFF_F1B = OFF_F1W + 4 * D_ * D_;  // 115072
constexpr int OFF_F2W = OFF_F1B + 4 * D_;       // 115584
constexpr int OFF_F2B = OFF_F2W + 4 * D_ * D_;  // 181120
constexpr int TP = 132;                          // LDS tile pitch (f32), 16B-aligned rows

typedef __attribute__((ext_vector_type(8))) short short8;
typedef __attribute__((ext_vector_type(4))) short short4v;
typedef __attribute__((ext_vector_type(2))) short short2v;
typedef __attribute__((ext_vector_type(4))) float f32x4;

#define MFMA16 __builtin_amdgcn_mfma_f32_16x16x32_bf16

__device__ __forceinline__ short f2bf(float f) {
  __hip_bfloat16 h = __float2bfloat16(f);
  return __builtin_bit_cast(short, h);
}
__device__ __forceinline__ float bf2f(short s) {
  __hip_bfloat16 h = __builtin_bit_cast(__hip_bfloat16, s);
  return __bfloat162float(h);
}
struct bfpair { short hi, lo; };
__device__ __forceinline__ bfpair split2p(float x) {
  bfpair p;
  p.hi = f2bf(x);
  p.lo = f2bf(x - bf2f(p.hi));
  return p;
}

// Fragment-tiled (FT) layout: matrix (rows, K) stored as 16x8 tiles:
// addr(row,k) = ((row>>4)*(K>>3) + (k>>3))*128 + (row&15)*8 + (k&7)
__device__ __forceinline__ long ftaddr(int row, int k, int K) {
  return ((long)(row >> 4) * (K >> 3) + (k >> 3)) * 128 + (row & 15) * 8 + (k & 7);
}

// ---------------- fp32 row-major -> FT split planes ----------------
__global__ void k_cvtft(const float* __restrict__ in, short* __restrict__ oh,
                        short* __restrict__ ol, int ktShift, int n8) {
  int t = blockIdx.x * 256 + threadIdx.x;
  if (t >= n8) return;
  int kt = 1 << ktShift;              // K/8
  int row = t >> ktShift;
  int kc = t & (kt - 1);
  const float* p = in + ((long)row << (ktShift + 3)) + kc * 8;
  float4 v0 = *(const float4*)p;
  float4 v1 = *(const float4*)(p + 4);
  short8 h8, l8;
  bfpair q;
  q = split2p(v0.x); h8[0] = q.hi; l8[0] = q.lo;
  q = split2p(v0.y); h8[1] = q.hi; l8[1] = q.lo;
  q = split2p(v0.z); h8[2] = q.hi; l8[2] = q.lo;
  q = split2p(v0.w); h8[3] = q.hi; l8[3] = q.lo;
  q = split2p(v1.x); h8[4] = q.hi; l8[4] = q.lo;
  q = split2p(v1.y); h8[5] = q.hi; l8[5] = q.lo;
  q = split2p(v1.z); h8[6] = q.hi; l8[6] = q.lo;
  q = split2p(v1.w); h8[7] = q.hi; l8[7] = q.lo;
  long o = ((long)(row >> 4) * kt + kc) * 128 + (row & 15) * 8;
  *(short8*)(oh + o) = h8;
  *(short8*)(ol + o) = l8;
}

// ---------------- hid = relu(ctx @ hfc1_w^T + b), FT planes (rows=32,K=512) --
__global__ __launch_bounds__(512) void k_hid(const float* __restrict__ cvec,
                                             const float* __restrict__ w,
                                             const float* __restrict__ bias,
                                             short* __restrict__ hh,
                                             short* __restrict__ hl) {
  int lb = blockIdx.x;            // l*32 + b
  int b  = lb & 31;
  int j  = threadIdx.x;
  __shared__ float cs[KCTX];
  if (j < KCTX) cs[j] = cvec[b * KCTX + j];
  __syncthreads();
  int l = lb >> 5;
  const float* wr = w + (long)(l * HID_ + j) * KCTX;
  float s = bias[l * HID_ + j];
  #pragma unroll
  for (int c = 0; c < KCTX; c += 4) {
    float4 cv = *(const float4*)(cs + c);
    float4 wv = *(const float4*)(wr + c);
    s += cv.x * wv.x + cv.y * wv.y + cv.z * wv.z + cv.w * wv.w;
  }
  s = fmaxf(s, 0.f);
  bfpair p = split2p(s);
  long o = (long)l * 32 * HID_ + ((long)(b >> 4) * 64 + (j >> 3)) * 128 + (b & 15) * 8 + (j & 7);
  hh[o] = p.hi;
  hl[o] = p.lo;
}

// ---------------- k_flat: flat = hid @ hfc2_w^T + b (LDS-staged, both layers) -
__device__ __forceinline__ void store_flat(int b, int trow, float v,
    short* __restrict__ awh, short* __restrict__ awl,
    short* __restrict__ f1h, short* __restrict__ f1l,
    short* __restrict__ f2h, short* __restrict__ f2l,
    float* __restrict__ ab, float* __restrict__ f1b, float* __restrict__ f2b) {
  if (trow < OFF_AB) {
    int e = trow >> 7, d = trow & 127;
    long a = (long)b * 49152 + ftaddr(e, d, 128);
    bfpair p = split2p(v); awh[a] = p.hi; awl[a] = p.lo;
  } else if (trow < OFF_F1W) {
    ab[b * 384 + trow - OFF_AB] = v;
  } else if (trow < OFF_F1B) {
    int i = trow - OFF_F1W; int f = i >> 7, d = i & 127;
    long a = (long)b * 65536 + ftaddr(f, d, 128);
    bfpair p = split2p(v); f1h[a] = p.hi; f1l[a] = p.lo;
  } else if (trow < OFF_F2W) {
    f1b[b * 512 + trow - OFF_F1B] = v;
  } else if (trow < OFF_F2B) {
    int i = trow - OFF_F2W; int dd = i >> 9, f = i & 511;
    long a = (long)b * 65536 + ftaddr(dd, f, 512);
    bfpair p = split2p(v); f2h[a] = p.hi; f2l[a] = p.lo;
  } else {
    f2b[b * 128 + trow - OFF_F2B] = v;
  }
}

__global__ __launch_bounds__(256) void k_flat(
    const short* __restrict__ hidh, const short* __restrict__ hidl,  // FT(32,512)
    const float* __restrict__ W, const float* __restrict__ bias,
    short* __restrict__ awh, short* __restrict__ awl,
    short* __restrict__ f1h, short* __restrict__ f1l,
    short* __restrict__ f2h, short* __restrict__ f2l,
    float* __restrict__ ab, float* __restrict__ f1b, float* __restrict__ f2b) {
  __shared__ short wls[2][64 * 64];   // 16 KB, swizzled
  const int l = blockIdx.y;
  hidh += (long)l * 32 * HID_;
  hidl += (long)l * 32 * HID_;
  W    += (long)l * TOTAL_ * HID_;
  bias += (long)l * TOTAL_;
  awh  += (long)l * B_ * 49152;  awl += (long)l * B_ * 49152;
  f1h  += (long)l * B_ * 65536;  f1l += (long)l * B_ * 65536;
  f2h  += (long)l * B_ * 65536;  f2l += (long)l * B_ * 65536;
  ab   += l * B_ * 384;  f1b += l * B_ * 512;  f2b += l * B_ * 128;
  const int tid = threadIdx.x, wave = tid >> 6, lane = tid & 63;
  const int r = lane & 15, g = lane >> 4;
  const int nb0 = blockIdx.x * 64;
  const int rr = tid >> 4;            // 0..15
  const int cc = (tid & 15) * 4;      // 0..60 (f32 col within chunk)
  const float* wbase = W + (long)nb0 * HID_;
  // 2-deep register prefetch
  float4 wv[2][4];
  #pragma unroll
  for (int rnd = 0; rnd < 4; ++rnd) {
    wv[0][rnd] = *(const float4*)(wbase + (long)(rnd * 16 + rr) * HID_ + cc);
    wv[1][rnd] = *(const float4*)(wbase + (long)(rnd * 16 + rr) * HID_ + 64 + cc);
  }
  const short* pAh = hidh + g * 128 + r * 8;
  const short* pAl = hidl + g * 128 + r * 8;
  f32x4 acc0 = {0, 0, 0, 0}, acc1 = {0, 0, 0, 0};
  int cur = 0;
  for (int c0 = 0; c0 < 512; c0 += 64) {
    #pragma unroll
    for (int rnd = 0; rnd < 4; ++rnd) {
      int row = rnd * 16 + rr;
      short4v h4, l4; bfpair q;
      q = split2p(wv[cur][rnd].x); h4[0] = q.hi; l4[0] = q.lo;
      q = split2p(wv[cur][rnd].y); h4[1] = q.hi; l4[1] = q.lo;
      q = split2p(wv[cur][rnd].z); h4[2] = q.hi; l4[2] = q.lo;
      q = split2p(wv[cur][rnd].w); h4[3] = q.hi; l4[3] = q.lo;
      int sb = row * 128 + ((cc * 2) ^ ((row & 7) << 4));   // byte offset in plane
      *(short4v*)((char*)&wls[0][0] + sb) = h4;
      *(short4v*)((char*)&wls[1][0] + sb) = l4;
    }
    if (c0 + 128 < 512) {
      #pragma unroll
      for (int rnd = 0; rnd < 4; ++rnd)
        wv[cur][rnd] = *(const float4*)(wbase + (long)(rnd * 16 + rr) * HID_ + (c0 + 128) + cc);
    }
    __syncthreads();
    #pragma unroll
    for (int kk = 0; kk < 2; ++kk) {
      long ao = (long)(c0 * 16) + kk * 512;
      short8 ah0 = *(const short8*)(pAh + ao);
      short8 ah1 = *(const short8*)(pAh + 8192 + ao);
      short8 al0 = *(const short8*)(pAl + ao);
      short8 al1 = *(const short8*)(pAl + 8192 + ao);
      int wrow = wave * 16 + r;
      int wb = wrow * 128 + ((kk * 64 + g * 16) ^ ((r & 7) << 4));   // byte offset
      short8 wh = *(const short8*)((char*)&wls[0][0] + wb);
      short8 wl = *(const short8*)((char*)&wls[1][0] + wb);
      acc0 = MFMA16(ah0, wl, acc0, 0, 0, 0);
      acc0 = MFMA16(al0, wh, acc0, 0, 0, 0);
      acc0 = MFMA16(ah0, wh, acc0, 0, 0, 0);
      acc1 = MFMA16(ah1, wl, acc1, 0, 0, 0);
      acc1 = MFMA16(al1, wh, acc1, 0, 0, 0);
      acc1 = MFMA16(ah1, wh, acc1, 0, 0, 0);
    }
    __syncthreads();
    cur ^= 1;
  }
  int trow = nb0 + wave * 16 + r;
  float bv = bias[trow];
  #pragma unroll
  for (int reg = 0; reg < 4; ++reg) {
    store_flat(g * 4 + reg, trow, acc0[reg] + bv, awh, awl, f1h, f1l, f2h, f2l, ab, f1b, f2b);
    store_flat(g * 4 + reg + 16, trow, acc1[reg] + bv, awh, awl, f1h, f1l, f2h, f2l, ab, f1b, f2b);
  }
}

// ---------------- generic batched split-MFMA GEMM, FT operands ----------------
// grid: (x = m-tile(64), y = n-tile(128), z = b).
// EPI: 0 = FT split planes out via LDS (p0,p1; pitch N); 1 = in_proj (+pe,
//      p0=h_f f32, p1/p2 FT planes); 4 = fused residual+LN (p0=h_f rw,
//      p1/p2 FT planes); 5 = qkv (y<2: qk FT via LDS p0/p1; y==2: vt short4 p2/p3).
template <int K, int EPI, bool RELU>
__global__ __launch_bounds__(256) void k_gemm(
    const short* __restrict__ Ah, const short* __restrict__ Al, long sA,
    const short* __restrict__ Wh, const short* __restrict__ Wl, long sW,
    const float* __restrict__ biasP, long sB,
    void* __restrict__ p0, void* __restrict__ p1,
    void* __restrict__ p2, void* __restrict__ p3,
    const float* __restrict__ pe, int N,
    const float* __restrict__ lng, const float* __restrict__ lnb,
    const float* __restrict__ lnal) {
  extern __shared__ char smem_dyn[];
  const int tid = threadIdx.x, wave = tid >> 6, lane = tid & 63;
  const int r = lane & 15, g = lane >> 4;
  const int b = blockIdx.z;
  const int m0 = blockIdx.x * 64 + (wave & 1) * 32;
  const int n0 = blockIdx.y * 128 + (wave >> 1) * 64;
  const long KT = (long)K * 16;
  const short* pAh = Ah + (long)b * sA + (m0 >> 4) * KT + g * 128 + r * 8;
  const short* pAl = Al + (long)b * sA + (m0 >> 4) * KT + g * 128 + r * 8;
  const short* pWh = Wh + (long)b * sW + (n0 >> 4) * KT + g * 128 + r * 8;
  const short* pWl = Wl + (long)b * sW + (n0 >> 4) * KT + g * 128 + r * 8;
  f32x4 acc[2][4] = {{{0,0,0,0},{0,0,0,0},{0,0,0,0},{0,0,0,0}},
                     {{0,0,0,0},{0,0,0,0},{0,0,0,0},{0,0,0,0}}};
  for (int kk = 0; kk < K / 32; ++kk) {
    long ko = (long)kk * 512;
    short8 a0h = *(const short8*)(pAh + ko);
    short8 a1h = *(const short8*)(pAh + KT + ko);
    short8 a0l = *(const short8*)(pAl + ko);
    short8 a1l = *(const short8*)(pAl + KT + ko);
    #pragma unroll
    for (int ns = 0; ns < 4; ++ns) {
      short8 wh = *(const short8*)(pWh + ns * KT + ko);
      short8 wl = *(const short8*)(pWl + ns * KT + ko);
      acc[0][ns] = MFMA16(a0h, wl, acc[0][ns], 0, 0, 0);
      acc[0][ns] = MFMA16(a0l, wh, acc[0][ns], 0, 0, 0);
      acc[0][ns] = MFMA16(a0h, wh, acc[0][ns], 0, 0, 0);
      acc[1][ns] = MFMA16(a1h, wl, acc[1][ns], 0, 0, 0);
      acc[1][ns] = MFMA16(a1l, wh, acc[1][ns], 0, 0, 0);
      acc[1][ns] = MFMA16(a1h, wh, acc[1][ns], 0, 0, 0);
    }
  }

  // ---- vt direct path (EPI 5, blockIdx.y == 2): reg-contiguous short4 stores
  if constexpr (EPI == 5) {
    if (blockIdx.y == 2) {
      #pragma unroll
      for (int ms = 0; ms < 2; ++ms) {
        int crow0 = m0 + ms * 16 + g * 4;
        #pragma unroll
        for (int ns = 0; ns < 4; ++ns) {
          int ccol = n0 + ns * 16 + r;
          float bv = biasP[(long)b * sB + ccol];
          int c2 = ccol - 256, hd = c2 >> 5, dd = c2 & 31;
          short4v h4, l4; bfpair q;
          #pragma unroll
          for (int reg = 0; reg < 4; ++reg) {
            float v = acc[ms][ns][reg] + bv;
            q = split2p(v); h4[reg] = q.hi; l4[reg] = q.lo;
          }
          long o = (long)(b * 4 + hd) * 16384 + (dd >> 4) * 8192
                 + (crow0 >> 3) * 128 + (dd & 15) * 8 + (crow0 & 7);
          *(short4v*)((short*)p2 + o) = h4;
          *(short4v*)((short*)p3 + o) = l4;
        }
      }
      return;
    }
  }

  if constexpr (EPI == 1) {
    #pragma unroll
    for (int ms = 0; ms < 2; ++ms) {
      #pragma unroll
      for (int ns = 0; ns < 4; ++ns) {
        int ccol = n0 + ns * 16 + r;
        float bv = biasP[ccol];
        #pragma unroll
        for (int reg = 0; reg < 4; ++reg) {
          int crow = m0 + ms * 16 + g * 4 + reg;
          float v = acc[ms][ns][reg] + bv + pe[crow * D_ + ccol];
          ((float*)p0)[((long)b * S_ + crow) * D_ + ccol] = v;
          long o = (long)b * 65536 + (long)(crow >> 4) * 2048
                 + (ccol >> 3) * 128 + (crow & 15) * 8 + (ccol & 7);
          bfpair sp = split2p(v);
          ((short*)p1)[o] = sp.hi;
          ((short*)p2)[o] = sp.lo;
        }
      }
    }
    return;
  }

  // ---- shared staging path (EPI 0, 4, 5-qk): stage f32 tile [64][TP]
  float* tile = (float*)smem_dyn;
  #pragma unroll
  for (int ms = 0; ms < 2; ++ms) {
    #pragma unroll
    for (int ns = 0; ns < 4; ++ns) {
      int ccol = n0 + ns * 16 + r;
      float bv = biasP[(long)b * sB + ccol];
      #pragma unroll
      for (int reg = 0; reg < 4; ++reg) {
        float v = acc[ms][ns][reg] + bv;
        if constexpr (RELU) v = fmaxf(v, 0.f);
        int trow2 = (wave & 1) * 32 + ms * 16 + g * 4 + reg;
        int tcol = (wave >> 1) * 64 + ns * 16 + r;
        tile[trow2 * TP + tcol] = v;
      }
    }
  }
  __syncthreads();

  if constexpr (EPI == 0 || EPI == 5) {
    // vectorized FT store: each thread owns one row x 32 cols (4x short8/plane)
    int row = tid >> 2, cg = tid & 3;
    int crow = blockIdx.x * 64 + row;
    long rowbase = (long)b * 512 * N + (long)(crow >> 4) * (16 * (long)N) + (crow & 15) * 8;
    #pragma unroll
    for (int j4 = 0; j4 < 4; ++j4) {
      int tcol = j4 * 32 + cg * 8;
      float4 aa = *(const float4*)&tile[row * TP + tcol];
      float4 bb = *(const float4*)&tile[row * TP + tcol + 4];
      short8 h8, l8; bfpair q;
      q = split2p(aa.x); h8[0] = q.hi; l8[0] = q.lo;
      q = split2p(aa.y); h8[1] = q.hi; l8[1] = q.lo;
      q = split2p(aa.z); h8[2] = q.hi; l8[2] = q.lo;
      q = split2p(aa.w); h8[3] = q.hi; l8[3] = q.lo;
      q = split2p(bb.x); h8[4] = q.hi; l8[4] = q.lo;
      q = split2p(bb.y); h8[5] = q.hi; l8[5] = q.lo;
      q = split2p(bb.z); h8[6] = q.hi; l8[6] = q.lo;
      q = split2p(bb.w); h8[7] = q.hi; l8[7] = q.lo;
      int ccol = blockIdx.y * 128 + tcol;
      long o = rowbase + (long)(ccol >> 3) * 128;
      *(short8*)((short*)p0 + o) = h8;
      *(short8*)((short*)p1 + o) = l8;
    }
  } else if constexpr (EPI == 4) {
    int row = tid >> 2, q = tid & 3;
    int brow = blockIdx.x * 64 + row;
    float a = lnal[0];
    float* hf = (float*)p0;
    float* hrow = hf + ((long)b * S_ + brow) * D_ + q * 32;
    float tv[32];
    float s = 0.f, ss = 0.f;
    #pragma unroll
    for (int i = 0; i < 32; i += 4) {
      float4 hv = *(const float4*)(hrow + i);
      float4 yv = *(const float4*)&tile[row * TP + q * 32 + i];
      float t0 = hv.x + a * yv.x, t1 = hv.y + a * yv.y;
      float t2 = hv.z + a * yv.z, t3 = hv.w + a * yv.w;
      tv[i] = t0; tv[i+1] = t1; tv[i+2] = t2; tv[i+3] = t3;
      s += t0 + t1 + t2 + t3;
      ss += t0*t0 + t1*t1 + t2*t2 + t3*t3;
    }
    s  += __shfl_xor(s, 1);  s  += __shfl_xor(s, 2);
    ss += __shfl_xor(ss, 1); ss += __shfl_xor(ss, 2);
    float mu = s * (1.f / 128.f);
    float varv = ss * (1.f / 128.f) - mu * mu;
    float inv = rsqrtf(varv + 1e-5f);
    short* ph = (short*)p1; short* pl = (short*)p2;
    long fb = (long)b * 65536 + (long)(brow >> 4) * 2048 + (brow & 15) * 8;
    #pragma unroll
    for (int j = 0; j < 4; ++j) {
      short8 hv8, lv8;
      #pragma unroll
      for (int e = 0; e < 8; e += 4) {
        int i = j * 8 + e;
        int c = q * 32 + i;
        float4 gv = *(const float4*)(lng + c);
        float4 bb = *(const float4*)(lnb + c);
        float4 o4;
        o4.x = (tv[i]   - mu) * inv * gv.x + bb.x;
        o4.y = (tv[i+1] - mu) * inv * gv.y + bb.y;
        o4.z = (tv[i+2] - mu) * inv * gv.z + bb.z;
        o4.w = (tv[i+3] - mu) * inv * gv.w + bb.w;
        *(float4*)(hrow + i) = o4;
        bfpair q0 = split2p(o4.x); hv8[e]   = q0.hi; lv8[e]   = q0.lo;
        bfpair q1 = split2p(o4.y); hv8[e+1] = q1.hi; lv8[e+1] = q1.lo;
        bfpair q2 = split2p(o4.z); hv8[e+2] = q2.hi; lv8[e+2] = q2.lo;
        bfpair q3 = split2p(o4.w); hv8[e+3] = q3.hi; lv8[e+3] = q3.lo;
      }
      long o = fb + (q * 4 + j) * 128;
      *(short8*)(ph + o) = hv8;
      *(short8*)(pl + o) = lv8;
    }
  }
}

// ---------------- attention: 16 q-rows/block, 2 cooperating waves ------------
__global__ __launch_bounds__(128) void k_attn(const short* __restrict__ qkh,
                                              const short* __restrict__ qkl,
                                              const short* __restrict__ vth,
                                              const short* __restrict__ vtl,
                                              short* __restrict__ ch,
                                              short* __restrict__ cl) {
  __shared__ __align__(16) float scr[16][516];   // 33 KB
  __shared__ __align__(16) float obuf[16][34];   // 2.2 KB
  const int tid = threadIdx.x, wave = tid >> 6, lane = tid & 63;
  const int r = lane & 15, g = lane >> 4;
  const int b = blockIdx.z, hh = blockIdx.y;
  const int m0 = blockIdx.x * 16;
  const long qb = (long)b * 131072;
  const long qoff = qb + (long)(m0 >> 4) * 4096 + (hh * 4 + g) * 128 + r * 8;
  short8 qh = *(const short8*)(qkh + qoff);
  short8 ql = *(const short8*)(qkl + qoff);
  const float sc = 0.17677669529663687f;  // 1/sqrt(32)
  for (int n0 = wave * 256; n0 < wave * 256 + 256; n0 += 16) {
    long koff = qb + (long)(n0 >> 4) * 4096 + (16 + hh * 4 + g) * 128 + r * 8;
    short8 kh = *(const short8*)(qkh + koff);
    short8 kl = *(const short8*)(qkl + koff);
    f32x4 s = {0, 0, 0, 0};
    s = MFMA16(qh, kl, s, 0, 0, 0);
    s = MFMA16(ql, kh, s, 0, 0, 0);
    s = MFMA16(qh, kh, s, 0, 0, 0);
    #pragma unroll
    for (int reg = 0; reg < 4; ++reg)
      scr[g * 4 + reg][n0 + r] = s[reg] * sc;
  }
  __syncthreads();
  for (int row = wave * 8; row < wave * 8 + 8; ++row) {
    float v[8];
    #pragma unroll
    for (int i = 0; i < 8; ++i) v[i] = scr[row][lane + i * 64];
    float m = v[0];
    #pragma unroll
    for (int i = 1; i < 8; ++i) m = fmaxf(m, v[i]);
    #pragma unroll
    for (int o = 32; o > 0; o >>= 1) m = fmaxf(m, __shfl_xor(m, o));
    float ssum = 0.f;
    #pragma unroll
    for (int i = 0; i < 8; ++i) { v[i] = __expf(v[i] - m); ssum += v[i]; }
    #pragma unroll
    for (int o = 32; o > 0; o >>= 1) ssum += __shfl_xor(ssum, o);
    float inv = 1.f / ssum;
    #pragma unroll
    for (int i = 0; i < 8; ++i) scr[row][lane + i * 64] = v[i] * inv;
  }
  __syncthreads();
  f32x4 o0 = {0, 0, 0, 0}, o1 = {0, 0, 0, 0};
  const long vb = (long)(b * 4 + hh) * 16384;
  for (int kt = wave * 8; kt < wave * 8 + 8; ++kt) {
    float4 pv0 = *(const float4*)&scr[r][kt * 32 + g * 8];
    float4 pv1 = *(const float4*)&scr[r][kt * 32 + g * 8 + 4];
    short8 pah, pal;
    bfpair p;
    p = split2p(pv0.x); pah[0] = p.hi; pal[0] = p.lo;
    p = split2p(pv0.y); pah[1] = p.hi; pal[1] = p.lo;
    p = split2p(pv0.z); pah[2] = p.hi; pal[2] = p.lo;
    p = split2p(pv0.w); pah[3] = p.hi; pal[3] = p.lo;
    p = split2p(pv1.x); pah[4] = p.hi; pal[4] = p.lo;
    p = split2p(pv1.y); pah[5] = p.hi; pal[5] = p.lo;
    p = split2p(pv1.z); pah[6] = p.hi; pal[6] = p.lo;
    p = split2p(pv1.w); pah[7] = p.hi; pal[7] = p.lo;
    long vo = vb + (long)(kt * 4 + g) * 128 + r * 8;
    short8 vh0 = *(const short8*)(vth + vo);
    short8 vh1 = *(const short8*)(vth + vo + 8192);
    short8 vl0 = *(const short8*)(vtl + vo);
    short8 vl1 = *(const short8*)(vtl + vo + 8192);
    o0 = MFMA16(pah, vl0, o0, 0, 0, 0);
    o0 = MFMA16(pal, vh0, o0, 0, 0, 0);
    o0 = MFMA16(pah, vh0, o0, 0, 0, 0);
    o1 = MFMA16(pah, vl1, o1, 0, 0, 0);
    o1 = MFMA16(pal, vh1, o1, 0, 0, 0);
    o1 = MFMA16(pah, vh1, o1, 0, 0, 0);
  }
  if (wave == 1) {
    #pragma unroll
    for (int reg = 0; reg < 4; ++reg) {
      obuf[g * 4 + reg][r] = o0[reg];
      obuf[g * 4 + reg][17 + r] = o1[reg];
    }
  }
  __syncthreads();
  if (wave == 0) {
    #pragma unroll
    for (int reg = 0; reg < 4; ++reg) {
      float a0 = o0[reg] + obuf[g * 4 + reg][r];
      float a1 = o1[reg] + obuf[g * 4 + reg][17 + r];
      int srow = m0 + g * 4 + reg;
      int col0 = hh * 32 + r;
      long o = (long)b * 65536 + (long)(srow >> 4) * 2048
             + (col0 >> 3) * 128 + (srow & 15) * 8 + (col0 & 7);
      bfpair sp0 = split2p(a0);
      ch[o] = sp0.hi; cl[o] = sp0.lo;
      long o2 = o + 2 * 128;
      bfpair sp1 = split2p(a1);
      ch[o2] = sp1.hi; cl[o2] = sp1.lo;
    }
  }
}

// ---------------- head ----------------
__global__ __launch_bounds__(64) void k_head(const float* __restrict__ h,
                                             const float* __restrict__ hw,
                                             const float* __restrict__ hb,
                                             float* __restrict__ out) {
  int b = blockIdx.x, lane = threadIdx.x;
  const float* hr = h + ((long)b * S_ + (S_ - 1)) * D_;
  float v = hr[lane] * hw[lane] + hr[lane + 64] * hw[lane + 64];
  #pragma unroll
  for (int o = 32; o > 0; o >>= 1) v += __shfl_xor(v, o);
  if (lane == 0) out[b] = v + hb[0];
}

// ---------------- host ----------------
extern "C" void kernel_launch(void* const* d_in, const int* in_sizes, int n_in,
                              void* d_out, int out_size, void* d_ws, size_t ws_size,
                              hipStream_t stream) {
  const float* x    = (const float*)d_in[0];
  const float* cvec = (const float*)d_in[1];
  const float* ipw  = (const float*)d_in[2];
  const float* ipb  = (const float*)d_in[3];
  const float* pe   = (const float*)d_in[4];
  const float* h1w  = (const float*)d_in[5];
  const float* h1b  = (const float*)d_in[6];
  const float* h2w  = (const float*)d_in[7];
  const float* h2b  = (const float*)d_in[8];
  const float* opw  = (const float*)d_in[9];
  const float* opb  = (const float*)d_in[10];
  const float* ln1g = (const float*)d_in[11];
  const float* ln1b = (const float*)d_in[12];
  const float* ln2g = (const float*)d_in[13];
  const float* ln2b = (const float*)d_in[14];
  const float* a1   = (const float*)d_in[15];
  const float* a2   = (const float*)d_in[16];
  const float* hw   = (const float*)d_in[17];
  const float* hb   = (const float*)d_in[18];
  float* out = (float*)d_out;

  char* ws = (char*)d_ws;
  size_t off = 0;
  auto alloc = [&](size_t n) { void* p = ws + off; off = (off + n + 255) & ~(size_t)255; return p; };

  const long AWs = (long)B_ * 49152;
  const long F1s = (long)B_ * 65536;
  const long F2s = (long)B_ * 65536;

  short* ff1h  = (short*)alloc((size_t)B_ * S_ * 512 * 2);   // aliases xFh
  short* ff1l  = (short*)alloc((size_t)B_ * S_ * 512 * 2);
  short* xFh   = ff1h;    // x planes dead before ff1 written
  short* xFl   = ff1l;
  float* h_f   = (float*)alloc((size_t)B_ * S_ * D_ * 4);
  short* hFh   = (short*)alloc((size_t)B_ * S_ * D_ * 2);
  short* hFl   = (short*)alloc((size_t)B_ * S_ * D_ * 2);
  short* hidFh = (short*)alloc((size_t)L_ * 32 * HID_ * 2);
  short* hidFl = (short*)alloc((size_t)L_ * 32 * HID_ * 2);
  short* awFh  = (short*)alloc((size_t)L_ * AWs * 2);
  short* awFl  = (short*)alloc((size_t)L_ * AWs * 2);
  short* f1wFh = (short*)alloc((size_t)L_ * F1s * 2);
  short* f1wFl = (short*)alloc((size_t)L_ * F1s * 2);
  short* f2wFh = (short*)alloc((size_t)L_ * F2s * 2);
  short* f2wFl = (short*)alloc((size_t)L_ * F2s * 2);
  float* abF   = (float*)alloc((size_t)L_ * B_ * 384 * 4);
  float* f1bF  = (float*)alloc((size_t)L_ * B_ * 512 * 4);
  float* f2bF  = (float*)alloc((size_t)L_ * B_ * 128 * 4);
  short* qkFh  = (short*)alloc((size_t)B_ * S_ * 256 * 2);
  short* qkFl  = (short*)alloc((size_t)B_ * S_ * 256 * 2);
  short* vtFh  = (short*)alloc((size_t)B_ * H_ * 32 * S_ * 2);
  short* vtFl  = (short*)alloc((size_t)B_ * H_ * 32 * S_ * 2);
  short* cxFh  = (short*)alloc((size_t)B_ * S_ * D_ * 2);
  short* cxFl  = (short*)alloc((size_t)B_ * S_ * D_ * 2);
  short* ipwFh = (short*)alloc((size_t)D_ * INDIM * 2);
  short* ipwFl = (short*)alloc((size_t)D_ * INDIM * 2);
  short* opwFh = (short*)alloc((size_t)L_ * D_ * D_ * 2);
  short* opwFl = (short*)alloc((size_t)L_ * D_ * D_ * 2);

  k_cvtft<<<(B_ * S_ * INDIM / 8 + 255) / 256, 256, 0, stream>>>(x, xFh, xFl, 5, B_ * S_ * INDIM / 8);
  k_cvtft<<<16, 256, 0, stream>>>(ipw, ipwFh, ipwFl, 5, D_ * INDIM / 8);
  k_cvtft<<<16, 256, 0, stream>>>(opw, opwFh, opwFl, 4, L_ * D_ * D_ / 8);

  k_hid<<<L_ * 32, 512, 0, stream>>>(cvec, h1w, h1b, hidFh, hidFl);

  // both layers' hypernet weights in one launch
  k_flat<<<dim3(TOTAL_ / 64, 2), 256, 0, stream>>>(
      hidFh, hidFl, h2w, h2b, awFh, awFl, f1wFh, f1wFl, f2wFh, f2wFl,
      abF, f1bF, f2bF);

  // h = x @ in_proj^T + b + pe
  k_gemm<INDIM, 1, false><<<dim3(8, 1, B_), 256, 0, stream>>>(
      xFh, xFl, (long)S_ * INDIM, ipwFh, ipwFl, 0, ipb, 0,
      h_f, hFh, hFl, nullptr, pe, 128, nullptr, nullptr, nullptr);

  constexpr size_t TILE_LDS = 64 * TP * 4;   // 33792
  for (int l = 0; l < L_; ++l) {
    // qkv fused (N=384): blocks y=0,1 -> qk planes (LDS-vectorized); y=2 -> vt
    k_gemm<D_, 5, false><<<dim3(8, 3, B_), 256, TILE_LDS, stream>>>(
        hFh, hFl, (long)S_ * D_, awFh + l * AWs, awFl + l * AWs, 49152,
        abF + l * B_ * 384, 384,
        qkFh, qkFl, vtFh, vtFl, nullptr, 256, nullptr, nullptr, nullptr);
    k_attn<<<dim3(S_ / 16, H_, B_), 128, 0, stream>>>(qkFh, qkFl, vtFh, vtFl, cxFh, cxFl);
    // out_proj + residual + LN1 fused
    k_gemm<D_, 4, false><<<dim3(8, 1, B_), 256, TILE_LDS, stream>>>(
        cxFh, cxFl, (long)S_ * D_, opwFh + l * 16384, opwFl + l * 16384, 0,
        opb + l * D_, 0, h_f, hFh, hFl, nullptr, nullptr, 128,
        ln1g + l * D_, ln1b + l * D_, a1 + l);
    // ffn1 (relu) -> ff1 FT(512,512), LDS-vectorized stores
    k_gemm<D_, 0, true><<<dim3(8, 4, B_), 256, TILE_LDS, stream>>>(
        hFh, hFl, (long)S_ * D_, f1wFh + l * F1s, f1wFl + l * F1s, 65536,
        f1bF + l * B_ * 512, 512,
        ff1h, ff1l, nullptr, nullptr, nullptr, 512, nullptr, nullptr, nullptr);
    // ffn2 + residual + LN2 fused
    k_gemm<512, 4, false><<<dim3(8, 1, B_), 256, TILE_LDS, stream>>>(
        ff1h, ff1l, (long)S_ * 512, f2wFh + l * F2s, f2wFl + l * F2s, 65536,
        f2bF + l * B_ * 128, 128,
        h_f, hFh, hFl, nullptr, nullptr, 128,
        ln2g + l * D_, ln2b + l * D_, a2 + l);
  }
  k_head<<<B_, 64, 0, stream>>>(h_f, hw, hb, out);
}

// Round 9
// 448.262 us; speedup vs baseline: 1.2453x; 1.1291x over previous
//
#include <hip/hip_runtime.h>
#include <hip/hip_bf16.h>

// ---------------- constants ----------------
constexpr int B_    = 32;
constexpr int S_    = 512;
constexpr int INDIM = 256;
constexpr int KCTX  = 128;
constexpr int D_    = 128;
constexpr int H_    = 4;
constexpr int L_    = 2;
constexpr int HID_  = 512;
constexpr int TOTAL_ = 11 * D_ * D_ + 8 * D_;   // 181248
constexpr int OFF_AB  = 3 * D_ * D_;            // 49152
constexpr int OFF_F1W = OFF_AB + 3 * D_;        // 49536
constexpr int OFF_F1B = OFF_F1W + 4 * D_ * D_;  // 115072
constexpr int OFF_F2W = OFF_F1B + 4 * D_;       // 115584
constexpr int OFF_F2B = OFF_F2W + 4 * D_ * D_;  // 181120
constexpr int TP = 132;                          // LDS tile pitch (f32)

typedef __attribute__((ext_vector_type(8))) short short8;
typedef __attribute__((ext_vector_type(4))) short short4v;
typedef __attribute__((ext_vector_type(2))) short short2v;
typedef __attribute__((ext_vector_type(4))) float f32x4;

#define MFMA16 __builtin_amdgcn_mfma_f32_16x16x32_bf16

__device__ __forceinline__ short f2bf(float f) {
  __hip_bfloat16 h = __float2bfloat16(f);
  return __builtin_bit_cast(short, h);
}
__device__ __forceinline__ float bf2f(short s) {
  __hip_bfloat16 h = __builtin_bit_cast(__hip_bfloat16, s);
  return __bfloat162float(h);
}
struct bfpair { short hi, lo; };
__device__ __forceinline__ bfpair split2p(float x) {
  bfpair p;
  p.hi = f2bf(x);
  p.lo = f2bf(x - bf2f(p.hi));
  return p;
}

// Fragment-tiled (FT) layout: matrix (rows, K) stored as 16x8 tiles:
// addr(row,k) = ((row>>4)*(K>>3) + (k>>3))*128 + (row&15)*8 + (k&7)
__device__ __forceinline__ long ftaddr(int row, int k, int K) {
  return ((long)(row >> 4) * (K >> 3) + (k >> 3)) * 128 + (row & 15) * 8 + (k & 7);
}

// ---------------- fp32 row-major -> FT split planes ----------------
__global__ void k_cvtft(const float* __restrict__ in, short* __restrict__ oh,
                        short* __restrict__ ol, int ktShift, int n8) {
  int t = blockIdx.x * 256 + threadIdx.x;
  if (t >= n8) return;
  int kt = 1 << ktShift;              // K/8
  int row = t >> ktShift;
  int kc = t & (kt - 1);
  const float* p = in + ((long)row << (ktShift + 3)) + kc * 8;
  float4 v0 = *(const float4*)p;
  float4 v1 = *(const float4*)(p + 4);
  short8 h8, l8;
  bfpair q;
  q = split2p(v0.x); h8[0] = q.hi; l8[0] = q.lo;
  q = split2p(v0.y); h8[1] = q.hi; l8[1] = q.lo;
  q = split2p(v0.z); h8[2] = q.hi; l8[2] = q.lo;
  q = split2p(v0.w); h8[3] = q.hi; l8[3] = q.lo;
  q = split2p(v1.x); h8[4] = q.hi; l8[4] = q.lo;
  q = split2p(v1.y); h8[5] = q.hi; l8[5] = q.lo;
  q = split2p(v1.z); h8[6] = q.hi; l8[6] = q.lo;
  q = split2p(v1.w); h8[7] = q.hi; l8[7] = q.lo;
  long o = ((long)(row >> 4) * kt + kc) * 128 + (row & 15) * 8;
  *(short8*)(oh + o) = h8;
  *(short8*)(ol + o) = l8;
}

// ---------------- hid = relu(ctx @ hfc1_w^T + b), FT planes (rows=32,K=512) --
__global__ __launch_bounds__(512) void k_hid(const float* __restrict__ cvec,
                                             const float* __restrict__ w,
                                             const float* __restrict__ bias,
                                             short* __restrict__ hh,
                                             short* __restrict__ hl) {
  int lb = blockIdx.x;            // l*32 + b
  int b  = lb & 31;
  int j  = threadIdx.x;
  __shared__ float cs[KCTX];
  if (j < KCTX) cs[j] = cvec[b * KCTX + j];
  __syncthreads();
  int l = lb >> 5;
  const float* wr = w + (long)(l * HID_ + j) * KCTX;
  float s = bias[l * HID_ + j];
  #pragma unroll
  for (int c = 0; c < KCTX; c += 4) {
    float4 cv = *(const float4*)(cs + c);
    float4 wv = *(const float4*)(wr + c);
    s += cv.x * wv.x + cv.y * wv.y + cv.z * wv.z + cv.w * wv.w;
  }
  s = fmaxf(s, 0.f);
  bfpair p = split2p(s);
  long o = (long)l * 32 * HID_ + ((long)(b >> 4) * 64 + (j >> 3)) * 128 + (b & 15) * 8 + (j & 7);
  hh[o] = p.hi;
  hl[o] = p.lo;
}

// ---------------- k_flat: flat = hid @ hfc2_w^T + b (LDS-staged, both layers) -
__global__ __launch_bounds__(256) void k_flat(
    const short* __restrict__ hidh, const short* __restrict__ hidl,  // FT(32,512)
    const float* __restrict__ W, const float* __restrict__ bias,
    short* __restrict__ awh, short* __restrict__ awl,
    short* __restrict__ f1h, short* __restrict__ f1l,
    short* __restrict__ f2h, short* __restrict__ f2l,
    float* __restrict__ ab, float* __restrict__ f1b, float* __restrict__ f2b) {
  __shared__ short wls[2][64 * 64];   // 16 KB, swizzled; reused as f32 C-tile
  const int l = blockIdx.y;
  hidh += (long)l * 32 * HID_;
  hidl += (long)l * 32 * HID_;
  W    += (long)l * TOTAL_ * HID_;
  bias += (long)l * TOTAL_;
  awh  += (long)l * B_ * 49152;  awl += (long)l * B_ * 49152;
  f1h  += (long)l * B_ * 65536;  f1l += (long)l * B_ * 65536;
  f2h  += (long)l * B_ * 65536;  f2l += (long)l * B_ * 65536;
  ab   += l * B_ * 384;  f1b += l * B_ * 512;  f2b += l * B_ * 128;
  const int tid = threadIdx.x, wave = tid >> 6, lane = tid & 63;
  const int r = lane & 15, g = lane >> 4;
  const int nb0 = blockIdx.x * 64;
  const int rr = tid >> 4;            // 0..15
  const int cc = (tid & 15) * 4;      // 0..60 (f32 col within chunk)
  const float* wbase = W + (long)nb0 * HID_;
  // 2-deep register prefetch
  float4 wv[2][4];
  #pragma unroll
  for (int rnd = 0; rnd < 4; ++rnd) {
    wv[0][rnd] = *(const float4*)(wbase + (long)(rnd * 16 + rr) * HID_ + cc);
    wv[1][rnd] = *(const float4*)(wbase + (long)(rnd * 16 + rr) * HID_ + 64 + cc);
  }
  const short* pAh = hidh + g * 128 + r * 8;
  const short* pAl = hidl + g * 128 + r * 8;
  f32x4 acc0 = {0, 0, 0, 0}, acc1 = {0, 0, 0, 0};
  int cur = 0;
  for (int c0 = 0; c0 < 512; c0 += 64) {
    #pragma unroll
    for (int rnd = 0; rnd < 4; ++rnd) {
      int row = rnd * 16 + rr;
      short4v h4, l4; bfpair q;
      q = split2p(wv[cur][rnd].x); h4[0] = q.hi; l4[0] = q.lo;
      q = split2p(wv[cur][rnd].y); h4[1] = q.hi; l4[1] = q.lo;
      q = split2p(wv[cur][rnd].z); h4[2] = q.hi; l4[2] = q.lo;
      q = split2p(wv[cur][rnd].w); h4[3] = q.hi; l4[3] = q.lo;
      int sb = row * 128 + ((cc * 2) ^ ((row & 7) << 4));   // byte offset in plane
      *(short4v*)((char*)&wls[0][0] + sb) = h4;
      *(short4v*)((char*)&wls[1][0] + sb) = l4;
    }
    if (c0 + 128 < 512) {
      #pragma unroll
      for (int rnd = 0; rnd < 4; ++rnd)
        wv[cur][rnd] = *(const float4*)(wbase + (long)(rnd * 16 + rr) * HID_ + (c0 + 128) + cc);
    }
    __syncthreads();
    #pragma unroll
    for (int kk = 0; kk < 2; ++kk) {
      long ao = (long)(c0 * 16) + kk * 512;
      short8 ah0 = *(const short8*)(pAh + ao);
      short8 ah1 = *(const short8*)(pAh + 8192 + ao);
      short8 al0 = *(const short8*)(pAl + ao);
      short8 al1 = *(const short8*)(pAl + 8192 + ao);
      int wrow = wave * 16 + r;
      int wb = wrow * 128 + ((kk * 64 + g * 16) ^ ((r & 7) << 4));   // byte offset
      short8 wh = *(const short8*)((char*)&wls[0][0] + wb);
      short8 wl = *(const short8*)((char*)&wls[1][0] + wb);
      acc0 = MFMA16(ah0, wl, acc0, 0, 0, 0);
      acc0 = MFMA16(al0, wh, acc0, 0, 0, 0);
      acc0 = MFMA16(ah0, wh, acc0, 0, 0, 0);
      acc1 = MFMA16(ah1, wl, acc1, 0, 0, 0);
      acc1 = MFMA16(al1, wh, acc1, 0, 0, 0);
      acc1 = MFMA16(ah1, wh, acc1, 0, 0, 0);
    }
    __syncthreads();
    cur ^= 1;
  }
  // ---- vectorized epilogue: stage C (32 b x 64 trow) in LDS, store short8 ----
  constexpr int TPF = 68;
  float* tile = (float*)&wls[0][0];   // 32*68*4 = 8704 B
  {
    int trow = nb0 + wave * 16 + r;
    float bv = bias[trow];
    int col = wave * 16 + r;
    #pragma unroll
    for (int reg = 0; reg < 4; ++reg) {
      tile[(g * 4 + reg) * TPF + col]        = acc0[reg] + bv;
      tile[(g * 4 + reg + 16) * TPF + col]   = acc1[reg] + bv;
    }
  }
  __syncthreads();
  {
    int b  = tid >> 3;           // 0..31
    int cg = tid & 7;            // 0..7
    int t0 = nb0 + cg * 8;       // 8-aligned group start; whole group same region
    float v[8];
    #pragma unroll
    for (int j = 0; j < 8; ++j) v[j] = tile[b * TPF + cg * 8 + j];
    if (t0 < OFF_AB) {
      int e = t0 >> 7, d = t0 & 127;
      long a = (long)b * 49152 + ((long)(e >> 4) * 16 + (d >> 3)) * 128 + (e & 15) * 8;
      short8 h8, l8; bfpair q;
      #pragma unroll
      for (int j = 0; j < 8; ++j) { q = split2p(v[j]); h8[j] = q.hi; l8[j] = q.lo; }
      *(short8*)(awh + a) = h8;
      *(short8*)(awl + a) = l8;
    } else if (t0 < OFF_F1W) {
      float* dst = ab + b * 384 + (t0 - OFF_AB);
      float4 x0 = {v[0], v[1], v[2], v[3]}, x1 = {v[4], v[5], v[6], v[7]};
      *(float4*)dst = x0; *(float4*)(dst + 4) = x1;
    } else if (t0 < OFF_F1B) {
      int i = t0 - OFF_F1W; int f = i >> 7, d = i & 127;
      long a = (long)b * 65536 + ((long)(f >> 4) * 16 + (d >> 3)) * 128 + (f & 15) * 8;
      short8 h8, l8; bfpair q;
      #pragma unroll
      for (int j = 0; j < 8; ++j) { q = split2p(v[j]); h8[j] = q.hi; l8[j] = q.lo; }
      *(short8*)(f1h + a) = h8;
      *(short8*)(f1l + a) = l8;
    } else if (t0 < OFF_F2W) {
      float* dst = f1b + b * 512 + (t0 - OFF_F1B);
      float4 x0 = {v[0], v[1], v[2], v[3]}, x1 = {v[4], v[5], v[6], v[7]};
      *(float4*)dst = x0; *(float4*)(dst + 4) = x1;
    } else if (t0 < OFF_F2B) {
      int i = t0 - OFF_F2W; int dd = i >> 9, f = i & 511;
      long a = (long)b * 65536 + ((long)(dd >> 4) * 64 + (f >> 3)) * 128 + (dd & 15) * 8;
      short8 h8, l8; bfpair q;
      #pragma unroll
      for (int j = 0; j < 8; ++j) { q = split2p(v[j]); h8[j] = q.hi; l8[j] = q.lo; }
      *(short8*)(f2h + a) = h8;
      *(short8*)(f2l + a) = l8;
    } else {
      float* dst = f2b + b * 128 + (t0 - OFF_F2B);
      float4 x0 = {v[0], v[1], v[2], v[3]}, x1 = {v[4], v[5], v[6], v[7]};
      *(float4*)dst = x0; *(float4*)(dst + 4) = x1;
    }
  }
}

// ---------------- generic batched split-MFMA GEMM, FT operands ----------------
// grid offsets mOff/nOff allow partial-range launches (layer-1 pruning).
// EPI: 0 = FT split planes out via LDS; 1 = in_proj (+pe); 4 = residual+LN;
//      5 = qkv (y+nOff<2: qk FT via LDS; ==2: vt short4 direct).
template <int K, int EPI, bool RELU>
__global__ __launch_bounds__(256) void k_gemm(
    const short* __restrict__ Ah, const short* __restrict__ Al, long sA,
    const short* __restrict__ Wh, const short* __restrict__ Wl, long sW,
    const float* __restrict__ biasP, long sB,
    void* __restrict__ p0, void* __restrict__ p1,
    void* __restrict__ p2, void* __restrict__ p3,
    const float* __restrict__ pe, int N,
    const float* __restrict__ lng, const float* __restrict__ lnb,
    const float* __restrict__ lnal, int mOff, int nOff) {
  extern __shared__ char smem_dyn[];
  const int tid = threadIdx.x, wave = tid >> 6, lane = tid & 63;
  const int r = lane & 15, g = lane >> 4;
  const int b = blockIdx.z;
  const int bx = blockIdx.x + mOff, by = blockIdx.y + nOff;
  const int m0 = bx * 64 + (wave & 1) * 32;
  const int n0 = by * 128 + (wave >> 1) * 64;
  const long KT = (long)K * 16;
  const short* pAh = Ah + (long)b * sA + (m0 >> 4) * KT + g * 128 + r * 8;
  const short* pAl = Al + (long)b * sA + (m0 >> 4) * KT + g * 128 + r * 8;
  const short* pWh = Wh + (long)b * sW + (n0 >> 4) * KT + g * 128 + r * 8;
  const short* pWl = Wl + (long)b * sW + (n0 >> 4) * KT + g * 128 + r * 8;
  f32x4 acc[2][4] = {{{0,0,0,0},{0,0,0,0},{0,0,0,0},{0,0,0,0}},
                     {{0,0,0,0},{0,0,0,0},{0,0,0,0},{0,0,0,0}}};
  for (int kk = 0; kk < K / 32; ++kk) {
    long ko = (long)kk * 512;
    short8 a0h = *(const short8*)(pAh + ko);
    short8 a1h = *(const short8*)(pAh + KT + ko);
    short8 a0l = *(const short8*)(pAl + ko);
    short8 a1l = *(const short8*)(pAl + KT + ko);
    #pragma unroll
    for (int ns = 0; ns < 4; ++ns) {
      short8 wh = *(const short8*)(pWh + ns * KT + ko);
      short8 wl = *(const short8*)(pWl + ns * KT + ko);
      acc[0][ns] = MFMA16(a0h, wl, acc[0][ns], 0, 0, 0);
      acc[0][ns] = MFMA16(a0l, wh, acc[0][ns], 0, 0, 0);
      acc[0][ns] = MFMA16(a0h, wh, acc[0][ns], 0, 0, 0);
      acc[1][ns] = MFMA16(a1h, wl, acc[1][ns], 0, 0, 0);
      acc[1][ns] = MFMA16(a1l, wh, acc[1][ns], 0, 0, 0);
      acc[1][ns] = MFMA16(a1h, wh, acc[1][ns], 0, 0, 0);
    }
  }

  // ---- vt direct path (EPI 5, by == 2): reg-contiguous short4 stores
  if constexpr (EPI == 5) {
    if (by == 2) {
      #pragma unroll
      for (int ms = 0; ms < 2; ++ms) {
        int crow0 = m0 + ms * 16 + g * 4;
        #pragma unroll
        for (int ns = 0; ns < 4; ++ns) {
          int ccol = n0 + ns * 16 + r;
          float bv = biasP[(long)b * sB + ccol];
          int c2 = ccol - 256, hd = c2 >> 5, dd = c2 & 31;
          short4v h4, l4; bfpair q;
          #pragma unroll
          for (int reg = 0; reg < 4; ++reg) {
            float v = acc[ms][ns][reg] + bv;
            q = split2p(v); h4[reg] = q.hi; l4[reg] = q.lo;
          }
          long o = (long)(b * 4 + hd) * 16384 + (dd >> 4) * 8192
                 + (crow0 >> 3) * 128 + (dd & 15) * 8 + (crow0 & 7);
          *(short4v*)((short*)p2 + o) = h4;
          *(short4v*)((short*)p3 + o) = l4;
        }
      }
      return;
    }
  }

  if constexpr (EPI == 1) {
    #pragma unroll
    for (int ms = 0; ms < 2; ++ms) {
      #pragma unroll
      for (int ns = 0; ns < 4; ++ns) {
        int ccol = n0 + ns * 16 + r;
        float bv = biasP[ccol];
        #pragma unroll
        for (int reg = 0; reg < 4; ++reg) {
          int crow = m0 + ms * 16 + g * 4 + reg;
          float v = acc[ms][ns][reg] + bv + pe[crow * D_ + ccol];
          ((float*)p0)[((long)b * S_ + crow) * D_ + ccol] = v;
          long o = (long)b * 65536 + (long)(crow >> 4) * 2048
                 + (ccol >> 3) * 128 + (crow & 15) * 8 + (ccol & 7);
          bfpair sp = split2p(v);
          ((short*)p1)[o] = sp.hi;
          ((short*)p2)[o] = sp.lo;
        }
      }
    }
    return;
  }

  // ---- shared staging path (EPI 0, 4, 5-qk): stage f32 tile [64][TP]
  float* tile = (float*)smem_dyn;
  #pragma unroll
  for (int ms = 0; ms < 2; ++ms) {
    #pragma unroll
    for (int ns = 0; ns < 4; ++ns) {
      int ccol = n0 + ns * 16 + r;
      float bv = biasP[(long)b * sB + ccol];
      #pragma unroll
      for (int reg = 0; reg < 4; ++reg) {
        float v = acc[ms][ns][reg] + bv;
        if constexpr (RELU) v = fmaxf(v, 0.f);
        int trow2 = (wave & 1) * 32 + ms * 16 + g * 4 + reg;
        int tcol = (wave >> 1) * 64 + ns * 16 + r;
        tile[trow2 * TP + tcol] = v;
      }
    }
  }
  __syncthreads();

  if constexpr (EPI == 0 || EPI == 5) {
    int row = tid >> 2, cg = tid & 3;
    int crow = bx * 64 + row;
    long rowbase = (long)b * 512 * N + (long)(crow >> 4) * (16 * (long)N) + (crow & 15) * 8;
    #pragma unroll
    for (int j4 = 0; j4 < 4; ++j4) {
      int tcol = j4 * 32 + cg * 8;
      float4 aa = *(const float4*)&tile[row * TP + tcol];
      float4 bb = *(const float4*)&tile[row * TP + tcol + 4];
      short8 h8, l8; bfpair q;
      q = split2p(aa.x); h8[0] = q.hi; l8[0] = q.lo;
      q = split2p(aa.y); h8[1] = q.hi; l8[1] = q.lo;
      q = split2p(aa.z); h8[2] = q.hi; l8[2] = q.lo;
      q = split2p(aa.w); h8[3] = q.hi; l8[3] = q.lo;
      q = split2p(bb.x); h8[4] = q.hi; l8[4] = q.lo;
      q = split2p(bb.y); h8[5] = q.hi; l8[5] = q.lo;
      q = split2p(bb.z); h8[6] = q.hi; l8[6] = q.lo;
      q = split2p(bb.w); h8[7] = q.hi; l8[7] = q.lo;
      int ccol = by * 128 + tcol;
      long o = rowbase + (long)(ccol >> 3) * 128;
      *(short8*)((short*)p0 + o) = h8;
      *(short8*)((short*)p1 + o) = l8;
    }
  } else if constexpr (EPI == 4) {
    int row = tid >> 2, q = tid & 3;
    int brow = bx * 64 + row;
    float a = lnal[0];
    float* hf = (float*)p0;
    float* hrow = hf + ((long)b * S_ + brow) * D_ + q * 32;
    float tv[32];
    float s = 0.f, ss = 0.f;
    #pragma unroll
    for (int i = 0; i < 32; i += 4) {
      float4 hv = *(const float4*)(hrow + i);
      float4 yv = *(const float4*)&tile[row * TP + q * 32 + i];
      float t0 = hv.x + a * yv.x, t1 = hv.y + a * yv.y;
      float t2 = hv.z + a * yv.z, t3 = hv.w + a * yv.w;
      tv[i] = t0; tv[i+1] = t1; tv[i+2] = t2; tv[i+3] = t3;
      s += t0 + t1 + t2 + t3;
      ss += t0*t0 + t1*t1 + t2*t2 + t3*t3;
    }
    s  += __shfl_xor(s, 1);  s  += __shfl_xor(s, 2);
    ss += __shfl_xor(ss, 1); ss += __shfl_xor(ss, 2);
    float mu = s * (1.f / 128.f);
    float varv = ss * (1.f / 128.f) - mu * mu;
    float inv = rsqrtf(varv + 1e-5f);
    short* ph = (short*)p1; short* pl = (short*)p2;
    long fb = (long)b * 65536 + (long)(brow >> 4) * 2048 + (brow & 15) * 8;
    #pragma unroll
    for (int j = 0; j < 4; ++j) {
      short8 hv8, lv8;
      #pragma unroll
      for (int e = 0; e < 8; e += 4) {
        int i = j * 8 + e;
        int c = q * 32 + i;
        float4 gv = *(const float4*)(lng + c);
        float4 bb = *(const float4*)(lnb + c);
        float4 o4;
        o4.x = (tv[i]   - mu) * inv * gv.x + bb.x;
        o4.y = (tv[i+1] - mu) * inv * gv.y + bb.y;
        o4.z = (tv[i+2] - mu) * inv * gv.z + bb.z;
        o4.w = (tv[i+3] - mu) * inv * gv.w + bb.w;
        *(float4*)(hrow + i) = o4;
        bfpair q0 = split2p(o4.x); hv8[e]   = q0.hi; lv8[e]   = q0.lo;
        bfpair q1 = split2p(o4.y); hv8[e+1] = q1.hi; lv8[e+1] = q1.lo;
        bfpair q2 = split2p(o4.z); hv8[e+2] = q2.hi; lv8[e+2] = q2.lo;
        bfpair q3 = split2p(o4.w); hv8[e+3] = q3.hi; lv8[e+3] = q3.lo;
      }
      long o = fb + (q * 4 + j) * 128;
      *(short8*)(ph + o) = hv8;
      *(short8*)(pl + o) = lv8;
    }
  }
}

// ---------------- attention: 16 q-rows/block, 2 cooperating waves ------------
__global__ __launch_bounds__(128) void k_attn(const short* __restrict__ qkh,
                                              const short* __restrict__ qkl,
                                              const short* __restrict__ vth,
                                              const short* __restrict__ vtl,
                                              short* __restrict__ ch,
                                              short* __restrict__ cl,
                                              int mOff) {
  __shared__ __align__(16) float scr[16][516];   // 33 KB
  __shared__ __align__(16) float obuf[16][34];   // 2.2 KB
  const int tid = threadIdx.x, wave = tid >> 6, lane = tid & 63;
  const int r = lane & 15, g = lane >> 4;
  const int b = blockIdx.z, hh = blockIdx.y;
  const int m0 = (blockIdx.x + mOff) * 16;
  const long qb = (long)b * 131072;
  const long qoff = qb + (long)(m0 >> 4) * 4096 + (hh * 4 + g) * 128 + r * 8;
  short8 qh = *(const short8*)(qkh + qoff);
  short8 ql = *(const short8*)(qkl + qoff);
  const float sc = 0.17677669529663687f;  // 1/sqrt(32)
  for (int n0 = wave * 256; n0 < wave * 256 + 256; n0 += 16) {
    long koff = qb + (long)(n0 >> 4) * 4096 + (16 + hh * 4 + g) * 128 + r * 8;
    short8 kh = *(const short8*)(qkh + koff);
    short8 kl = *(const short8*)(qkl + koff);
    f32x4 s = {0, 0, 0, 0};
    s = MFMA16(qh, kl, s, 0, 0, 0);
    s = MFMA16(ql, kh, s, 0, 0, 0);
    s = MFMA16(qh, kh, s, 0, 0, 0);
    #pragma unroll
    for (int reg = 0; reg < 4; ++reg)
      scr[g * 4 + reg][n0 + r] = s[reg] * sc;
  }
  __syncthreads();
  for (int row = wave * 8; row < wave * 8 + 8; ++row) {
    float v[8];
    #pragma unroll
    for (int i = 0; i < 8; ++i) v[i] = scr[row][lane + i * 64];
    float m = v[0];
    #pragma unroll
    for (int i = 1; i < 8; ++i) m = fmaxf(m, v[i]);
    #pragma unroll
    for (int o = 32; o > 0; o >>= 1) m = fmaxf(m, __shfl_xor(m, o));
    float ssum = 0.f;
    #pragma unroll
    for (int i = 0; i < 8; ++i) { v[i] = __expf(v[i] - m); ssum += v[i]; }
    #pragma unroll
    for (int o = 32; o > 0; o >>= 1) ssum += __shfl_xor(ssum, o);
    float inv = 1.f / ssum;
    #pragma unroll
    for (int i = 0; i < 8; ++i) scr[row][lane + i * 64] = v[i] * inv;
  }
  __syncthreads();
  f32x4 o0 = {0, 0, 0, 0}, o1 = {0, 0, 0, 0};
  const long vb = (long)(b * 4 + hh) * 16384;
  for (int kt = wave * 8; kt < wave * 8 + 8; ++kt) {
    float4 pv0 = *(const float4*)&scr[r][kt * 32 + g * 8];
    float4 pv1 = *(const float4*)&scr[r][kt * 32 + g * 8 + 4];
    short8 pah, pal;
    bfpair p;
    p = split2p(pv0.x); pah[0] = p.hi; pal[0] = p.lo;
    p = split2p(pv0.y); pah[1] = p.hi; pal[1] = p.lo;
    p = split2p(pv0.z); pah[2] = p.hi; pal[2] = p.lo;
    p = split2p(pv0.w); pah[3] = p.hi; pal[3] = p.lo;
    p = split2p(pv1.x); pah[4] = p.hi; pal[4] = p.lo;
    p = split2p(pv1.y); pah[5] = p.hi; pal[5] = p.lo;
    p = split2p(pv1.z); pah[6] = p.hi; pal[6] = p.lo;
    p = split2p(pv1.w); pah[7] = p.hi; pal[7] = p.lo;
    long vo = vb + (long)(kt * 4 + g) * 128 + r * 8;
    short8 vh0 = *(const short8*)(vth + vo);
    short8 vh1 = *(const short8*)(vth + vo + 8192);
    short8 vl0 = *(const short8*)(vtl + vo);
    short8 vl1 = *(const short8*)(vtl + vo + 8192);
    o0 = MFMA16(pah, vl0, o0, 0, 0, 0);
    o0 = MFMA16(pal, vh0, o0, 0, 0, 0);
    o0 = MFMA16(pah, vh0, o0, 0, 0, 0);
    o1 = MFMA16(pah, vl1, o1, 0, 0, 0);
    o1 = MFMA16(pal, vh1, o1, 0, 0, 0);
    o1 = MFMA16(pah, vh1, o1, 0, 0, 0);
  }
  if (wave == 1) {
    #pragma unroll
    for (int reg = 0; reg < 4; ++reg) {
      obuf[g * 4 + reg][r] = o0[reg];
      obuf[g * 4 + reg][17 + r] = o1[reg];
    }
  }
  __syncthreads();
  if (wave == 0) {
    #pragma unroll
    for (int reg = 0; reg < 4; ++reg) {
      float a0 = o0[reg] + obuf[g * 4 + reg][r];
      float a1 = o1[reg] + obuf[g * 4 + reg][17 + r];
      int srow = m0 + g * 4 + reg;
      int col0 = hh * 32 + r;
      long o = (long)b * 65536 + (long)(srow >> 4) * 2048
             + (col0 >> 3) * 128 + (srow & 15) * 8 + (col0 & 7);
      bfpair sp0 = split2p(a0);
      ch[o] = sp0.hi; cl[o] = sp0.lo;
      long o2 = o + 2 * 128;
      bfpair sp1 = split2p(a1);
      ch[o2] = sp1.hi; cl[o2] = sp1.lo;
    }
  }
}

// ---------------- head ----------------
__global__ __launch_bounds__(64) void k_head(const float* __restrict__ h,
                                             const float* __restrict__ hw,
                                             const float* __restrict__ hb,
                                             float* __restrict__ out) {
  int b = blockIdx.x, lane = threadIdx.x;
  const float* hr = h + ((long)b * S_ + (S_ - 1)) * D_;
  float v = hr[lane] * hw[lane] + hr[lane + 64] * hw[lane + 64];
  #pragma unroll
  for (int o = 32; o > 0; o >>= 1) v += __shfl_xor(v, o);
  if (lane == 0) out[b] = v + hb[0];
}

// ---------------- host ----------------
extern "C" void kernel_launch(void* const* d_in, const int* in_sizes, int n_in,
                              void* d_out, int out_size, void* d_ws, size_t ws_size,
                              hipStream_t stream) {
  const float* x    = (const float*)d_in[0];
  const float* cvec = (const float*)d_in[1];
  const float* ipw  = (const float*)d_in[2];
  const float* ipb  = (const float*)d_in[3];
  const float* pe   = (const float*)d_in[4];
  const float* h1w  = (const float*)d_in[5];
  const float* h1b  = (const float*)d_in[6];
  const float* h2w  = (const float*)d_in[7];
  const float* h2b  = (const float*)d_in[8];
  const float* opw  = (const float*)d_in[9];
  const float* opb  = (const float*)d_in[10];
  const float* ln1g = (const float*)d_in[11];
  const float* ln1b = (const float*)d_in[12];
  const float* ln2g = (const float*)d_in[13];
  const float* ln2b = (const float*)d_in[14];
  const float* a1   = (const float*)d_in[15];
  const float* a2   = (const float*)d_in[16];
  const float* hw   = (const float*)d_in[17];
  const float* hb   = (const float*)d_in[18];
  float* out = (float*)d_out;

  char* ws = (char*)d_ws;
  size_t off = 0;
  auto alloc = [&](size_t n) { void* p = ws + off; off = (off + n + 255) & ~(size_t)255; return p; };

  const long AWs = (long)B_ * 49152;
  const long F1s = (long)B_ * 65536;
  const long F2s = (long)B_ * 65536;

  short* ff1h  = (short*)alloc((size_t)B_ * S_ * 512 * 2);   // aliases xFh
  short* ff1l  = (short*)alloc((size_t)B_ * S_ * 512 * 2);
  short* xFh   = ff1h;    // x planes dead before ff1 written
  short* xFl   = ff1l;
  float* h_f   = (float*)alloc((size_t)B_ * S_ * D_ * 4);
  short* hFh   = (short*)alloc((size_t)B_ * S_ * D_ * 2);
  short* hFl   = (short*)alloc((size_t)B_ * S_ * D_ * 2);
  short* hidFh = (short*)alloc((size_t)L_ * 32 * HID_ * 2);
  short* hidFl = (short*)alloc((size_t)L_ * 32 * HID_ * 2);
  short* awFh  = (short*)alloc((size_t)L_ * AWs * 2);
  short* awFl  = (short*)alloc((size_t)L_ * AWs * 2);
  short* f1wFh = (short*)alloc((size_t)L_ * F1s * 2);
  short* f1wFl = (short*)alloc((size_t)L_ * F1s * 2);
  short* f2wFh = (short*)alloc((size_t)L_ * F2s * 2);
  short* f2wFl = (short*)alloc((size_t)L_ * F2s * 2);
  float* abF   = (float*)alloc((size_t)L_ * B_ * 384 * 4);
  float* f1bF  = (float*)alloc((size_t)L_ * B_ * 512 * 4);
  float* f2bF  = (float*)alloc((size_t)L_ * B_ * 128 * 4);
  short* qkFh  = (short*)alloc((size_t)B_ * S_ * 256 * 2);
  short* qkFl  = (short*)alloc((size_t)B_ * S_ * 256 * 2);
  short* vtFh  = (short*)alloc((size_t)B_ * H_ * 32 * S_ * 2);
  short* vtFl  = (short*)alloc((size_t)B_ * H_ * 32 * S_ * 2);
  short* cxFh  = (short*)alloc((size_t)B_ * S_ * D_ * 2);
  short* cxFl  = (short*)alloc((size_t)B_ * S_ * D_ * 2);
  short* ipwFh = (short*)alloc((size_t)D_ * INDIM * 2);
  short* ipwFl = (short*)alloc((size_t)D_ * INDIM * 2);
  short* opwFh = (short*)alloc((size_t)L_ * D_ * D_ * 2);
  short* opwFl = (short*)alloc((size_t)L_ * D_ * D_ * 2);

  k_cvtft<<<(B_ * S_ * INDIM / 8 + 255) / 256, 256, 0, stream>>>(x, xFh, xFl, 5, B_ * S_ * INDIM / 8);
  k_cvtft<<<16, 256, 0, stream>>>(ipw, ipwFh, ipwFl, 5, D_ * INDIM / 8);
  k_cvtft<<<16, 256, 0, stream>>>(opw, opwFh, opwFl, 4, L_ * D_ * D_ / 8);

  k_hid<<<L_ * 32, 512, 0, stream>>>(cvec, h1w, h1b, hidFh, hidFl);

  // both layers' hypernet weights in one launch
  k_flat<<<dim3(TOTAL_ / 64, 2), 256, 0, stream>>>(
      hidFh, hidFl, h2w, h2b, awFh, awFl, f1wFh, f1wFl, f2wFh, f2wFl,
      abF, f1bF, f2bF);

  // h = x @ in_proj^T + b + pe
  k_gemm<INDIM, 1, false><<<dim3(8, 1, B_), 256, 0, stream>>>(
      xFh, xFl, (long)S_ * INDIM, ipwFh, ipwFl, 0, ipb, 0,
      h_f, hFh, hFl, nullptr, pe, 128, nullptr, nullptr, nullptr, 0, 0);

  constexpr size_t TILE_LDS = 64 * TP * 4;   // 33792

  // ===== layer 0 (full) =====
  {
    int l = 0;
    k_gemm<D_, 5, false><<<dim3(8, 3, B_), 256, TILE_LDS, stream>>>(
        hFh, hFl, (long)S_ * D_, awFh + l * AWs, awFl + l * AWs, 49152,
        abF + l * B_ * 384, 384,
        qkFh, qkFl, vtFh, vtFl, nullptr, 256, nullptr, nullptr, nullptr, 0, 0);
    k_attn<<<dim3(S_ / 16, H_, B_), 128, 0, stream>>>(qkFh, qkFl, vtFh, vtFl, cxFh, cxFl, 0);
    k_gemm<D_, 4, false><<<dim3(8, 1, B_), 256, TILE_LDS, stream>>>(
        cxFh, cxFl, (long)S_ * D_, opwFh + l * 16384, opwFl + l * 16384, 0,
        opb + l * D_, 0, h_f, hFh, hFl, nullptr, nullptr, 128,
        ln1g + l * D_, ln1b + l * D_, a1 + l, 0, 0);
    k_gemm<D_, 0, true><<<dim3(8, 4, B_), 256, TILE_LDS, stream>>>(
        hFh, hFl, (long)S_ * D_, f1wFh + l * F1s, f1wFl + l * F1s, 65536,
        f1bF + l * B_ * 512, 512,
        ff1h, ff1l, nullptr, nullptr, nullptr, 512, nullptr, nullptr, nullptr, 0, 0);
    k_gemm<512, 4, false><<<dim3(8, 1, B_), 256, TILE_LDS, stream>>>(
        ff1h, ff1l, (long)S_ * 512, f2wFh + l * F2s, f2wFl + l * F2s, 65536,
        f2bF + l * B_ * 128, 128,
        h_f, hFh, hFl, nullptr, nullptr, 128,
        ln2g + l * D_, ln2b + l * D_, a2 + l, 0, 0);
  }

  // ===== layer 1 (pruned: only row 511 reaches the head) =====
  {
    int l = 1;
    // k,v for all rows (n-tiles 1,2)
    k_gemm<D_, 5, false><<<dim3(8, 2, B_), 256, TILE_LDS, stream>>>(
        hFh, hFl, (long)S_ * D_, awFh + l * AWs, awFl + l * AWs, 49152,
        abF + l * B_ * 384, 384,
        qkFh, qkFl, vtFh, vtFl, nullptr, 256, nullptr, nullptr, nullptr, 0, 1);
    // q only for last m-tile (rows 448..511)
    k_gemm<D_, 5, false><<<dim3(1, 1, B_), 256, TILE_LDS, stream>>>(
        hFh, hFl, (long)S_ * D_, awFh + l * AWs, awFl + l * AWs, 49152,
        abF + l * B_ * 384, 384,
        qkFh, qkFl, vtFh, vtFl, nullptr, 256, nullptr, nullptr, nullptr, 7, 0);
    // attention only for q-rows 496..511
    k_attn<<<dim3(1, H_, B_), 128, 0, stream>>>(qkFh, qkFl, vtFh, vtFl, cxFh, cxFl, 31);
    // out_proj + LN1 only for rows 448..511
    k_gemm<D_, 4, false><<<dim3(1, 1, B_), 256, TILE_LDS, stream>>>(
        cxFh, cxFl, (long)S_ * D_, opwFh + l * 16384, opwFl + l * 16384, 0,
        opb + l * D_, 0, h_f, hFh, hFl, nullptr, nullptr, 128,
        ln1g + l * D_, ln1b + l * D_, a1 + l, 7, 0);
    // ffn1 only for rows 448..511
    k_gemm<D_, 0, true><<<dim3(1, 4, B_), 256, TILE_LDS, stream>>>(
        hFh, hFl, (long)S_ * D_, f1wFh + l * F1s, f1wFl + l * F1s, 65536,
        f1bF + l * B_ * 512, 512,
        ff1h, ff1l, nullptr, nullptr, nullptr, 512, nullptr, nullptr, nullptr, 7, 0);
    // ffn2 + LN2 only for rows 448..511
    k_gemm<512, 4, false><<<dim3(1, 1, B_), 256, TILE_LDS, stream>>>(
        ff1h, ff1l, (long)S_ * 512, f2wFh + l * F2s, f2wFl + l * F2s, 65536,
        f2bF + l * B_ * 128, 128,
        h_f, hFh, hFl, nullptr, nullptr, 128,
        ln2g + l * D_, ln2b + l * D_, a2 + l, 7, 0);
  }
  k_head<<<B_, 64, 0, stream>>>(h_f, hw, hb, out);
}

// Round 10
// 440.165 us; speedup vs baseline: 1.2682x; 1.0184x over previous
//
#include <hip/hip_runtime.h>
#include <hip/hip_bf16.h>

// ---------------- constants ----------------
constexpr int B_    = 32;
constexpr int S_    = 512;
constexpr int INDIM = 256;
constexpr int KCTX  = 128;
constexpr int D_    = 128;
constexpr int H_    = 4;
constexpr int L_    = 2;
constexpr int HID_  = 512;
constexpr int TOTAL_ = 11 * D_ * D_ + 8 * D_;   // 181248
constexpr int OFF_AB  = 3 * D_ * D_;            // 49152
constexpr int OFF_F1W = OFF_AB + 3 * D_;        // 49536
constexpr int OFF_F1B = OFF_F1W + 4 * D_ * D_;  // 115072
constexpr int OFF_F2W = OFF_F1B + 4 * D_;       // 115584
constexpr int OFF_F2B = OFF_F2W + 4 * D_ * D_;  // 181120
constexpr int TP = 132;                          // LDS tile pitch (f32)

typedef __attribute__((ext_vector_type(8))) short short8;
typedef __attribute__((ext_vector_type(4))) short short4v;
typedef __attribute__((ext_vector_type(2))) short short2v;
typedef __attribute__((ext_vector_type(4))) float f32x4;

#define MFMA16 __builtin_amdgcn_mfma_f32_16x16x32_bf16

__device__ __forceinline__ short f2bf(float f) {
  __hip_bfloat16 h = __float2bfloat16(f);
  return __builtin_bit_cast(short, h);
}
__device__ __forceinline__ float bf2f(short s) {
  __hip_bfloat16 h = __builtin_bit_cast(__hip_bfloat16, s);
  return __bfloat162float(h);
}
struct bfpair { short hi, lo; };
__device__ __forceinline__ bfpair split2p(float x) {
  bfpair p;
  p.hi = f2bf(x);
  p.lo = f2bf(x - bf2f(p.hi));
  return p;
}

// ---------------- prep: cvt x/ipw/opw + hid, one dispatch ----------------
__device__ __forceinline__ void cvt_body(const float* __restrict__ in,
                                         short* __restrict__ oh,
                                         short* __restrict__ ol,
                                         int ktShift, int n8, int t) {
  if (t >= n8) return;
  int kt = 1 << ktShift;
  int row = t >> ktShift;
  int kc = t & (kt - 1);
  const float* p = in + ((long)row << (ktShift + 3)) + kc * 8;
  float4 v0 = *(const float4*)p;
  float4 v1 = *(const float4*)(p + 4);
  short8 h8, l8; bfpair q;
  q = split2p(v0.x); h8[0] = q.hi; l8[0] = q.lo;
  q = split2p(v0.y); h8[1] = q.hi; l8[1] = q.lo;
  q = split2p(v0.z); h8[2] = q.hi; l8[2] = q.lo;
  q = split2p(v0.w); h8[3] = q.hi; l8[3] = q.lo;
  q = split2p(v1.x); h8[4] = q.hi; l8[4] = q.lo;
  q = split2p(v1.y); h8[5] = q.hi; l8[5] = q.lo;
  q = split2p(v1.z); h8[6] = q.hi; l8[6] = q.lo;
  q = split2p(v1.w); h8[7] = q.hi; l8[7] = q.lo;
  long o = ((long)(row >> 4) * kt + kc) * 128 + (row & 15) * 8;
  *(short8*)(oh + o) = h8;
  *(short8*)(ol + o) = l8;
}

__global__ __launch_bounds__(256) void k_prep(
    const float* __restrict__ x, const float* __restrict__ ipw,
    const float* __restrict__ opw,
    short* __restrict__ xFh, short* __restrict__ xFl,
    short* __restrict__ ipwFh, short* __restrict__ ipwFl,
    short* __restrict__ opwFh, short* __restrict__ opwFl,
    const float* __restrict__ cvec, const float* __restrict__ h1w,
    const float* __restrict__ h1b,
    short* __restrict__ hidFh, short* __restrict__ hidFl) {
  int id = blockIdx.x, tid = threadIdx.x;
  if (id < 2048) {
    cvt_body(x, xFh, xFl, 5, B_ * S_ * INDIM / 8, id * 256 + tid);
  } else if (id < 2064) {
    cvt_body(ipw, ipwFh, ipwFl, 5, D_ * INDIM / 8, (id - 2048) * 256 + tid);
  } else if (id < 2080) {
    cvt_body(opw, opwFh, opwFl, 4, L_ * D_ * D_ / 8, (id - 2064) * 256 + tid);
  } else {
    int hb = id - 2080;           // 0..63
    int l = hb >> 5, b = hb & 31;
    __shared__ float cs[KCTX];
    if (tid < KCTX) cs[tid] = cvec[b * KCTX + tid];
    __syncthreads();
    #pragma unroll
    for (int jj = 0; jj < 2; ++jj) {
      int j = tid + jj * 256;
      const float* wr = h1w + (long)(l * HID_ + j) * KCTX;
      float s = h1b[l * HID_ + j];
      #pragma unroll
      for (int c = 0; c < KCTX; c += 4) {
        float4 cv = *(const float4*)(cs + c);
        float4 wv = *(const float4*)(wr + c);
        s += cv.x * wv.x + cv.y * wv.y + cv.z * wv.z + cv.w * wv.w;
      }
      s = fmaxf(s, 0.f);
      bfpair p = split2p(s);
      long o = (long)l * 32 * HID_ + ((long)(b >> 4) * 64 + (j >> 3)) * 128
             + (b & 15) * 8 + (j & 7);
      hidFh[o] = p.hi;
      hidFl[o] = p.lo;
    }
  }
}

// ---------------- k_flat_ip: in_proj blocks + flat (both layers) ------------
__device__ void inproj_block(int id,
    const short* __restrict__ xFh, const short* __restrict__ xFl,
    const short* __restrict__ ipwFh, const short* __restrict__ ipwFl,
    const float* __restrict__ ipb, const float* __restrict__ pe,
    float* __restrict__ h_f, short* __restrict__ hFh, short* __restrict__ hFl) {
  const int tid = threadIdx.x, wave = tid >> 6, lane = tid & 63;
  const int r = lane & 15, g = lane >> 4;
  const int bx = id >> 5, b = id & 31;
  const int m0 = bx * 64 + (wave & 1) * 32;
  const int n0 = (wave >> 1) * 64;
  const long KT = (long)INDIM * 16;   // 4096
  const short* pAh = xFh + (long)b * S_ * INDIM + (m0 >> 4) * KT + g * 128 + r * 8;
  const short* pAl = xFl + (long)b * S_ * INDIM + (m0 >> 4) * KT + g * 128 + r * 8;
  const short* pWh = ipwFh + (n0 >> 4) * KT + g * 128 + r * 8;
  const short* pWl = ipwFl + (n0 >> 4) * KT + g * 128 + r * 8;
  f32x4 acc[2][4] = {{{0,0,0,0},{0,0,0,0},{0,0,0,0},{0,0,0,0}},
                     {{0,0,0,0},{0,0,0,0},{0,0,0,0},{0,0,0,0}}};
  for (int kk = 0; kk < INDIM / 32; ++kk) {
    long ko = (long)kk * 512;
    short8 a0h = *(const short8*)(pAh + ko);
    short8 a1h = *(const short8*)(pAh + KT + ko);
    short8 a0l = *(const short8*)(pAl + ko);
    short8 a1l = *(const short8*)(pAl + KT + ko);
    #pragma unroll
    for (int ns = 0; ns < 4; ++ns) {
      short8 wh = *(const short8*)(pWh + ns * KT + ko);
      short8 wl = *(const short8*)(pWl + ns * KT + ko);
      acc[0][ns] = MFMA16(a0h, wl, acc[0][ns], 0, 0, 0);
      acc[0][ns] = MFMA16(a0l, wh, acc[0][ns], 0, 0, 0);
      acc[0][ns] = MFMA16(a0h, wh, acc[0][ns], 0, 0, 0);
      acc[1][ns] = MFMA16(a1h, wl, acc[1][ns], 0, 0, 0);
      acc[1][ns] = MFMA16(a1l, wh, acc[1][ns], 0, 0, 0);
      acc[1][ns] = MFMA16(a1h, wh, acc[1][ns], 0, 0, 0);
    }
  }
  #pragma unroll
  for (int ms = 0; ms < 2; ++ms) {
    #pragma unroll
    for (int ns = 0; ns < 4; ++ns) {
      int ccol = n0 + ns * 16 + r;
      float bv = ipb[ccol];
      #pragma unroll
      for (int reg = 0; reg < 4; ++reg) {
        int crow = m0 + ms * 16 + g * 4 + reg;
        float v = acc[ms][ns][reg] + bv + pe[crow * D_ + ccol];
        h_f[((long)b * S_ + crow) * D_ + ccol] = v;
        long o = (long)b * 65536 + (long)(crow >> 4) * 2048
               + (ccol >> 3) * 128 + (crow & 15) * 8 + (ccol & 7);
        bfpair sp = split2p(v);
        hFh[o] = sp.hi;
        hFl[o] = sp.lo;
      }
    }
  }
}

__global__ __launch_bounds__(256) void k_flat_ip(
    const short* __restrict__ hidh, const short* __restrict__ hidl,
    const float* __restrict__ W, const float* __restrict__ bias,
    short* __restrict__ awh, short* __restrict__ awl,
    short* __restrict__ f1h, short* __restrict__ f1l,
    short* __restrict__ f2h, short* __restrict__ f2l,
    float* __restrict__ ab, float* __restrict__ f1b, float* __restrict__ f2b,
    const short* __restrict__ xFh, const short* __restrict__ xFl,
    const short* __restrict__ ipwFh, const short* __restrict__ ipwFl,
    const float* __restrict__ ipb, const float* __restrict__ pe,
    float* __restrict__ h_f, short* __restrict__ hFh, short* __restrict__ hFl) {
  __shared__ short wls[2][64 * 64];   // 16 KB, swizzled; reused as f32 C-tile
  const int id = blockIdx.x;
  if (id < 256) {
    inproj_block(id, xFh, xFl, ipwFh, ipwFl, ipb, pe, h_f, hFh, hFl);
    return;
  }
  const int fid = id - 256;
  const int l = fid / 2832;
  const int bxf = fid % 2832;
  hidh += (long)l * 32 * HID_;
  hidl += (long)l * 32 * HID_;
  W    += (long)l * TOTAL_ * HID_;
  bias += (long)l * TOTAL_;
  awh  += (long)l * B_ * 49152;  awl += (long)l * B_ * 49152;
  f1h  += (long)l * B_ * 65536;  f1l += (long)l * B_ * 65536;
  f2h  += (long)l * B_ * 65536;  f2l += (long)l * B_ * 65536;
  ab   += l * B_ * 384;  f1b += l * B_ * 512;  f2b += l * B_ * 128;
  const int tid = threadIdx.x, wave = tid >> 6, lane = tid & 63;
  const int r = lane & 15, g = lane >> 4;
  const int nb0 = bxf * 64;
  const int rr = tid >> 4;            // 0..15
  const int cc = (tid & 15) * 4;      // 0..60
  const float* wbase = W + (long)nb0 * HID_;
  float4 wv[2][4];
  #pragma unroll
  for (int rnd = 0; rnd < 4; ++rnd) {
    wv[0][rnd] = *(const float4*)(wbase + (long)(rnd * 16 + rr) * HID_ + cc);
    wv[1][rnd] = *(const float4*)(wbase + (long)(rnd * 16 + rr) * HID_ + 64 + cc);
  }
  const short* pAh = hidh + g * 128 + r * 8;
  const short* pAl = hidl + g * 128 + r * 8;
  f32x4 acc0 = {0, 0, 0, 0}, acc1 = {0, 0, 0, 0};
  int cur = 0;
  for (int c0 = 0; c0 < 512; c0 += 64) {
    #pragma unroll
    for (int rnd = 0; rnd < 4; ++rnd) {
      int row = rnd * 16 + rr;
      short4v h4, l4; bfpair q;
      q = split2p(wv[cur][rnd].x); h4[0] = q.hi; l4[0] = q.lo;
      q = split2p(wv[cur][rnd].y); h4[1] = q.hi; l4[1] = q.lo;
      q = split2p(wv[cur][rnd].z); h4[2] = q.hi; l4[2] = q.lo;
      q = split2p(wv[cur][rnd].w); h4[3] = q.hi; l4[3] = q.lo;
      int sb = row * 128 + ((cc * 2) ^ ((row & 7) << 4));
      *(short4v*)((char*)&wls[0][0] + sb) = h4;
      *(short4v*)((char*)&wls[1][0] + sb) = l4;
    }
    if (c0 + 128 < 512) {
      #pragma unroll
      for (int rnd = 0; rnd < 4; ++rnd)
        wv[cur][rnd] = *(const float4*)(wbase + (long)(rnd * 16 + rr) * HID_ + (c0 + 128) + cc);
    }
    __syncthreads();
    #pragma unroll
    for (int kk = 0; kk < 2; ++kk) {
      long ao = (long)(c0 * 16) + kk * 512;
      short8 ah0 = *(const short8*)(pAh + ao);
      short8 ah1 = *(const short8*)(pAh + 8192 + ao);
      short8 al0 = *(const short8*)(pAl + ao);
      short8 al1 = *(const short8*)(pAl + 8192 + ao);
      int wrow = wave * 16 + r;
      int wb = wrow * 128 + ((kk * 64 + g * 16) ^ ((r & 7) << 4));
      short8 wh = *(const short8*)((char*)&wls[0][0] + wb);
      short8 wl = *(const short8*)((char*)&wls[1][0] + wb);
      acc0 = MFMA16(ah0, wl, acc0, 0, 0, 0);
      acc0 = MFMA16(al0, wh, acc0, 0, 0, 0);
      acc0 = MFMA16(ah0, wh, acc0, 0, 0, 0);
      acc1 = MFMA16(ah1, wl, acc1, 0, 0, 0);
      acc1 = MFMA16(al1, wh, acc1, 0, 0, 0);
      acc1 = MFMA16(ah1, wh, acc1, 0, 0, 0);
    }
    __syncthreads();
    cur ^= 1;
  }
  // vectorized epilogue via LDS
  constexpr int TPF = 68;
  float* tile = (float*)&wls[0][0];
  {
    float bv = bias[nb0 + wave * 16 + r];
    int col = wave * 16 + r;
    #pragma unroll
    for (int reg = 0; reg < 4; ++reg) {
      tile[(g * 4 + reg) * TPF + col]      = acc0[reg] + bv;
      tile[(g * 4 + reg + 16) * TPF + col] = acc1[reg] + bv;
    }
  }
  __syncthreads();
  {
    int b  = tid >> 3;
    int cg = tid & 7;
    int t0 = nb0 + cg * 8;
    float v[8];
    #pragma unroll
    for (int j = 0; j < 8; ++j) v[j] = tile[b * TPF + cg * 8 + j];
    if (t0 < OFF_AB) {
      int e = t0 >> 7, d = t0 & 127;
      long a = (long)b * 49152 + ((long)(e >> 4) * 16 + (d >> 3)) * 128 + (e & 15) * 8;
      short8 h8, l8; bfpair q;
      #pragma unroll
      for (int j = 0; j < 8; ++j) { q = split2p(v[j]); h8[j] = q.hi; l8[j] = q.lo; }
      *(short8*)(awh + a) = h8;
      *(short8*)(awl + a) = l8;
    } else if (t0 < OFF_F1W) {
      float* dst = ab + b * 384 + (t0 - OFF_AB);
      float4 x0 = {v[0], v[1], v[2], v[3]}, x1 = {v[4], v[5], v[6], v[7]};
      *(float4*)dst = x0; *(float4*)(dst + 4) = x1;
    } else if (t0 < OFF_F1B) {
      int i = t0 - OFF_F1W; int f = i >> 7, d = i & 127;
      long a = (long)b * 65536 + ((long)(f >> 4) * 16 + (d >> 3)) * 128 + (f & 15) * 8;
      short8 h8, l8; bfpair q;
      #pragma unroll
      for (int j = 0; j < 8; ++j) { q = split2p(v[j]); h8[j] = q.hi; l8[j] = q.lo; }
      *(short8*)(f1h + a) = h8;
      *(short8*)(f1l + a) = l8;
    } else if (t0 < OFF_F2W) {
      float* dst = f1b + b * 512 + (t0 - OFF_F1B);
      float4 x0 = {v[0], v[1], v[2], v[3]}, x1 = {v[4], v[5], v[6], v[7]};
      *(float4*)dst = x0; *(float4*)(dst + 4) = x1;
    } else if (t0 < OFF_F2B) {
      int i = t0 - OFF_F2W; int dd = i >> 9, f = i & 511;
      long a = (long)b * 65536 + ((long)(dd >> 4) * 64 + (f >> 3)) * 128 + (dd & 15) * 8;
      short8 h8, l8; bfpair q;
      #pragma unroll
      for (int j = 0; j < 8; ++j) { q = split2p(v[j]); h8[j] = q.hi; l8[j] = q.lo; }
      *(short8*)(f2h + a) = h8;
      *(short8*)(f2l + a) = l8;
    } else {
      float* dst = f2b + b * 128 + (t0 - OFF_F2B);
      float4 x0 = {v[0], v[1], v[2], v[3]}, x1 = {v[4], v[5], v[6], v[7]};
      *(float4*)dst = x0; *(float4*)(dst + 4) = x1;
    }
  }
}

// ---------------- generic batched split-MFMA GEMM, FT operands ----------------
// mode 0: bx=blockIdx.x+mOff, by=blockIdx.y+nOff.
// mode 1 (layer-1 qkv): x<16 -> (x>>1, 1+(x&1)); x==16 -> (7,0).
// EPI: 0 = FT planes via LDS; 4 = residual+LN; 5 = qkv (by<2 qk, by==2 vt).
template <int K, int EPI, bool RELU>
__global__ __launch_bounds__(256) void k_gemm(
    const short* __restrict__ Ah, const short* __restrict__ Al, long sA,
    const short* __restrict__ Wh, const short* __restrict__ Wl, long sW,
    const float* __restrict__ biasP, long sB,
    void* __restrict__ p0, void* __restrict__ p1,
    void* __restrict__ p2, void* __restrict__ p3,
    int N,
    const float* __restrict__ lng, const float* __restrict__ lnb,
    const float* __restrict__ lnal, int mOff, int nOff, int mode) {
  extern __shared__ char smem_dyn[];
  const int tid = threadIdx.x, wave = tid >> 6, lane = tid & 63;
  const int r = lane & 15, g = lane >> 4;
  const int b = blockIdx.z;
  int bx, by;
  if (mode == 1) {
    int xx = blockIdx.x;
    if (xx < 16) { bx = xx >> 1; by = 1 + (xx & 1); }
    else         { bx = 7; by = 0; }
  } else {
    bx = blockIdx.x + mOff; by = blockIdx.y + nOff;
  }
  const int m0 = bx * 64 + (wave & 1) * 32;
  const int n0 = by * 128 + (wave >> 1) * 64;
  const long KT = (long)K * 16;
  const short* pAh = Ah + (long)b * sA + (m0 >> 4) * KT + g * 128 + r * 8;
  const short* pAl = Al + (long)b * sA + (m0 >> 4) * KT + g * 128 + r * 8;
  const short* pWh = Wh + (long)b * sW + (n0 >> 4) * KT + g * 128 + r * 8;
  const short* pWl = Wl + (long)b * sW + (n0 >> 4) * KT + g * 128 + r * 8;
  f32x4 acc[2][4] = {{{0,0,0,0},{0,0,0,0},{0,0,0,0},{0,0,0,0}},
                     {{0,0,0,0},{0,0,0,0},{0,0,0,0},{0,0,0,0}}};
  for (int kk = 0; kk < K / 32; ++kk) {
    long ko = (long)kk * 512;
    short8 a0h = *(const short8*)(pAh + ko);
    short8 a1h = *(const short8*)(pAh + KT + ko);
    short8 a0l = *(const short8*)(pAl + ko);
    short8 a1l = *(const short8*)(pAl + KT + ko);
    #pragma unroll
    for (int ns = 0; ns < 4; ++ns) {
      short8 wh = *(const short8*)(pWh + ns * KT + ko);
      short8 wl = *(const short8*)(pWl + ns * KT + ko);
      acc[0][ns] = MFMA16(a0h, wl, acc[0][ns], 0, 0, 0);
      acc[0][ns] = MFMA16(a0l, wh, acc[0][ns], 0, 0, 0);
      acc[0][ns] = MFMA16(a0h, wh, acc[0][ns], 0, 0, 0);
      acc[1][ns] = MFMA16(a1h, wl, acc[1][ns], 0, 0, 0);
      acc[1][ns] = MFMA16(a1l, wh, acc[1][ns], 0, 0, 0);
      acc[1][ns] = MFMA16(a1h, wh, acc[1][ns], 0, 0, 0);
    }
  }

  if constexpr (EPI == 5) {
    if (by == 2) {
      #pragma unroll
      for (int ms = 0; ms < 2; ++ms) {
        int crow0 = m0 + ms * 16 + g * 4;
        #pragma unroll
        for (int ns = 0; ns < 4; ++ns) {
          int ccol = n0 + ns * 16 + r;
          float bv = biasP[(long)b * sB + ccol];
          int c2 = ccol - 256, hd = c2 >> 5, dd = c2 & 31;
          short4v h4, l4; bfpair q;
          #pragma unroll
          for (int reg = 0; reg < 4; ++reg) {
            float v = acc[ms][ns][reg] + bv;
            q = split2p(v); h4[reg] = q.hi; l4[reg] = q.lo;
          }
          long o = (long)(b * 4 + hd) * 16384 + (dd >> 4) * 8192
                 + (crow0 >> 3) * 128 + (dd & 15) * 8 + (crow0 & 7);
          *(short4v*)((short*)p2 + o) = h4;
          *(short4v*)((short*)p3 + o) = l4;
        }
      }
      return;
    }
  }

  float* tile = (float*)smem_dyn;
  #pragma unroll
  for (int ms = 0; ms < 2; ++ms) {
    #pragma unroll
    for (int ns = 0; ns < 4; ++ns) {
      int ccol = n0 + ns * 16 + r;
      float bv = biasP[(long)b * sB + ccol];
      #pragma unroll
      for (int reg = 0; reg < 4; ++reg) {
        float v = acc[ms][ns][reg] + bv;
        if constexpr (RELU) v = fmaxf(v, 0.f);
        int trow2 = (wave & 1) * 32 + ms * 16 + g * 4 + reg;
        int tcol = (wave >> 1) * 64 + ns * 16 + r;
        tile[trow2 * TP + tcol] = v;
      }
    }
  }
  __syncthreads();

  if constexpr (EPI == 0 || EPI == 5) {
    int row = tid >> 2, cg = tid & 3;
    int crow = bx * 64 + row;
    long rowbase = (long)b * 512 * N + (long)(crow >> 4) * (16 * (long)N) + (crow & 15) * 8;
    #pragma unroll
    for (int j4 = 0; j4 < 4; ++j4) {
      int tcol = j4 * 32 + cg * 8;
      float4 aa = *(const float4*)&tile[row * TP + tcol];
      float4 bb = *(const float4*)&tile[row * TP + tcol + 4];
      short8 h8, l8; bfpair q;
      q = split2p(aa.x); h8[0] = q.hi; l8[0] = q.lo;
      q = split2p(aa.y); h8[1] = q.hi; l8[1] = q.lo;
      q = split2p(aa.z); h8[2] = q.hi; l8[2] = q.lo;
      q = split2p(aa.w); h8[3] = q.hi; l8[3] = q.lo;
      q = split2p(bb.x); h8[4] = q.hi; l8[4] = q.lo;
      q = split2p(bb.y); h8[5] = q.hi; l8[5] = q.lo;
      q = split2p(bb.z); h8[6] = q.hi; l8[6] = q.lo;
      q = split2p(bb.w); h8[7] = q.hi; l8[7] = q.lo;
      int ccol = by * 128 + tcol;
      long o = rowbase + (long)(ccol >> 3) * 128;
      *(short8*)((short*)p0 + o) = h8;
      *(short8*)((short*)p1 + o) = l8;
    }
  } else if constexpr (EPI == 4) {
    int row = tid >> 2, q = tid & 3;
    int brow = bx * 64 + row;
    float a = lnal[0];
    float* hf = (float*)p0;
    float* hrow = hf + ((long)b * S_ + brow) * D_ + q * 32;
    float tv[32];
    float s = 0.f, ss = 0.f;
    #pragma unroll
    for (int i = 0; i < 32; i += 4) {
      float4 hv = *(const float4*)(hrow + i);
      float4 yv = *(const float4*)&tile[row * TP + q * 32 + i];
      float t0 = hv.x + a * yv.x, t1 = hv.y + a * yv.y;
      float t2 = hv.z + a * yv.z, t3 = hv.w + a * yv.w;
      tv[i] = t0; tv[i+1] = t1; tv[i+2] = t2; tv[i+3] = t3;
      s += t0 + t1 + t2 + t3;
      ss += t0*t0 + t1*t1 + t2*t2 + t3*t3;
    }
    s  += __shfl_xor(s, 1);  s  += __shfl_xor(s, 2);
    ss += __shfl_xor(ss, 1); ss += __shfl_xor(ss, 2);
    float mu = s * (1.f / 128.f);
    float varv = ss * (1.f / 128.f) - mu * mu;
    float inv = rsqrtf(varv + 1e-5f);
    short* ph = (short*)p1; short* pl = (short*)p2;
    long fb = (long)b * 65536 + (long)(brow >> 4) * 2048 + (brow & 15) * 8;
    #pragma unroll
    for (int j = 0; j < 4; ++j) {
      short8 hv8, lv8;
      #pragma unroll
      for (int e = 0; e < 8; e += 4) {
        int i = j * 8 + e;
        int c = q * 32 + i;
        float4 gv = *(const float4*)(lng + c);
        float4 bb = *(const float4*)(lnb + c);
        float4 o4;
        o4.x = (tv[i]   - mu) * inv * gv.x + bb.x;
        o4.y = (tv[i+1] - mu) * inv * gv.y + bb.y;
        o4.z = (tv[i+2] - mu) * inv * gv.z + bb.z;
        o4.w = (tv[i+3] - mu) * inv * gv.w + bb.w;
        *(float4*)(hrow + i) = o4;
        bfpair q0 = split2p(o4.x); hv8[e]   = q0.hi; lv8[e]   = q0.lo;
        bfpair q1 = split2p(o4.y); hv8[e+1] = q1.hi; lv8[e+1] = q1.lo;
        bfpair q2 = split2p(o4.z); hv8[e+2] = q2.hi; lv8[e+2] = q2.lo;
        bfpair q3 = split2p(o4.w); hv8[e+3] = q3.hi; lv8[e+3] = q3.lo;
      }
      long o = fb + (q * 4 + j) * 128;
      *(short8*)(ph + o) = hv8;
      *(short8*)(pl + o) = lv8;
    }
  }
}

// ---------------- attention: 16 q-rows/block, 2 cooperating waves ------------
__global__ __launch_bounds__(128) void k_attn(const short* __restrict__ qkh,
                                              const short* __restrict__ qkl,
                                              const short* __restrict__ vth,
                                              const short* __restrict__ vtl,
                                              short* __restrict__ ch,
                                              short* __restrict__ cl,
                                              int mOff) {
  __shared__ __align__(16) float scr[16][516];   // 33 KB
  __shared__ __align__(16) float obuf[16][34];   // 2.2 KB
  const int tid = threadIdx.x, wave = tid >> 6, lane = tid & 63;
  const int r = lane & 15, g = lane >> 4;
  const int b = blockIdx.z, hh = blockIdx.y;
  const int m0 = (blockIdx.x + mOff) * 16;
  const long qb = (long)b * 131072;
  const long qoff = qb + (long)(m0 >> 4) * 4096 + (hh * 4 + g) * 128 + r * 8;
  short8 qh = *(const short8*)(qkh + qoff);
  short8 ql = *(const short8*)(qkl + qoff);
  const float sc = 0.17677669529663687f;  // 1/sqrt(32)
  for (int n0 = wave * 256; n0 < wave * 256 + 256; n0 += 16) {
    long koff = qb + (long)(n0 >> 4) * 4096 + (16 + hh * 4 + g) * 128 + r * 8;
    short8 kh = *(const short8*)(qkh + koff);
    short8 kl = *(const short8*)(qkl + koff);
    f32x4 s = {0, 0, 0, 0};
    s = MFMA16(qh, kl, s, 0, 0, 0);
    s = MFMA16(ql, kh, s, 0, 0, 0);
    s = MFMA16(qh, kh, s, 0, 0, 0);
    #pragma unroll
    for (int reg = 0; reg < 4; ++reg)
      scr[g * 4 + reg][n0 + r] = s[reg] * sc;
  }
  __syncthreads();
  for (int row = wave * 8; row < wave * 8 + 8; ++row) {
    float v[8];
    #pragma unroll
    for (int i = 0; i < 8; ++i) v[i] = scr[row][lane + i * 64];
    float m = v[0];
    #pragma unroll
    for (int i = 1; i < 8; ++i) m = fmaxf(m, v[i]);
    #pragma unroll
    for (int o = 32; o > 0; o >>= 1) m = fmaxf(m, __shfl_xor(m, o));
    float ssum = 0.f;
    #pragma unroll
    for (int i = 0; i < 8; ++i) { v[i] = __expf(v[i] - m); ssum += v[i]; }
    #pragma unroll
    for (int o = 32; o > 0; o >>= 1) ssum += __shfl_xor(ssum, o);
    float inv = 1.f / ssum;
    #pragma unroll
    for (int i = 0; i < 8; ++i) scr[row][lane + i * 64] = v[i] * inv;
  }
  __syncthreads();
  f32x4 o0 = {0, 0, 0, 0}, o1 = {0, 0, 0, 0};
  const long vb = (long)(b * 4 + hh) * 16384;
  for (int kt = wave * 8; kt < wave * 8 + 8; ++kt) {
    float4 pv0 = *(const float4*)&scr[r][kt * 32 + g * 8];
    float4 pv1 = *(const float4*)&scr[r][kt * 32 + g * 8 + 4];
    short8 pah, pal;
    bfpair p;
    p = split2p(pv0.x); pah[0] = p.hi; pal[0] = p.lo;
    p = split2p(pv0.y); pah[1] = p.hi; pal[1] = p.lo;
    p = split2p(pv0.z); pah[2] = p.hi; pal[2] = p.lo;
    p = split2p(pv0.w); pah[3] = p.hi; pal[3] = p.lo;
    p = split2p(pv1.x); pah[4] = p.hi; pal[4] = p.lo;
    p = split2p(pv1.y); pah[5] = p.hi; pal[5] = p.lo;
    p = split2p(pv1.z); pah[6] = p.hi; pal[6] = p.lo;
    p = split2p(pv1.w); pah[7] = p.hi; pal[7] = p.lo;
    long vo = vb + (long)(kt * 4 + g) * 128 + r * 8;
    short8 vh0 = *(const short8*)(vth + vo);
    short8 vh1 = *(const short8*)(vth + vo + 8192);
    short8 vl0 = *(const short8*)(vtl + vo);
    short8 vl1 = *(const short8*)(vtl + vo + 8192);
    o0 = MFMA16(pah, vl0, o0, 0, 0, 0);
    o0 = MFMA16(pal, vh0, o0, 0, 0, 0);
    o0 = MFMA16(pah, vh0, o0, 0, 0, 0);
    o1 = MFMA16(pah, vl1, o1, 0, 0, 0);
    o1 = MFMA16(pal, vh1, o1, 0, 0, 0);
    o1 = MFMA16(pah, vh1, o1, 0, 0, 0);
  }
  if (wave == 1) {
    #pragma unroll
    for (int reg = 0; reg < 4; ++reg) {
      obuf[g * 4 + reg][r] = o0[reg];
      obuf[g * 4 + reg][17 + r] = o1[reg];
    }
  }
  __syncthreads();
  if (wave == 0) {
    #pragma unroll
    for (int reg = 0; reg < 4; ++reg) {
      float a0 = o0[reg] + obuf[g * 4 + reg][r];
      float a1 = o1[reg] + obuf[g * 4 + reg][17 + r];
      int srow = m0 + g * 4 + reg;
      int col0 = hh * 32 + r;
      long o = (long)b * 65536 + (long)(srow >> 4) * 2048
             + (col0 >> 3) * 128 + (srow & 15) * 8 + (col0 & 7);
      bfpair sp0 = split2p(a0);
      ch[o] = sp0.hi; cl[o] = sp0.lo;
      long o2 = o + 2 * 128;
      bfpair sp1 = split2p(a1);
      ch[o2] = sp1.hi; cl[o2] = sp1.lo;
    }
  }
}

// ---------------- head ----------------
__global__ __launch_bounds__(64) void k_head(const float* __restrict__ h,
                                             const float* __restrict__ hw,
                                             const float* __restrict__ hb,
                                             float* __restrict__ out) {
  int b = blockIdx.x, lane = threadIdx.x;
  const float* hr = h + ((long)b * S_ + (S_ - 1)) * D_;
  float v = hr[lane] * hw[lane] + hr[lane + 64] * hw[lane + 64];
  #pragma unroll
  for (int o = 32; o > 0; o >>= 1) v += __shfl_xor(v, o);
  if (lane == 0) out[b] = v + hb[0];
}

// ---------------- host ----------------
extern "C" void kernel_launch(void* const* d_in, const int* in_sizes, int n_in,
                              void* d_out, int out_size, void* d_ws, size_t ws_size,
                              hipStream_t stream) {
  const float* x    = (const float*)d_in[0];
  const float* cvec = (const float*)d_in[1];
  const float* ipw  = (const float*)d_in[2];
  const float* ipb  = (const float*)d_in[3];
  const float* pe   = (const float*)d_in[4];
  const float* h1w  = (const float*)d_in[5];
  const float* h1b  = (const float*)d_in[6];
  const float* h2w  = (const float*)d_in[7];
  const float* h2b  = (const float*)d_in[8];
  const float* opw  = (const float*)d_in[9];
  const float* opb  = (const float*)d_in[10];
  const float* ln1g = (const float*)d_in[11];
  const float* ln1b = (const float*)d_in[12];
  const float* ln2g = (const float*)d_in[13];
  const float* ln2b = (const float*)d_in[14];
  const float* a1   = (const float*)d_in[15];
  const float* a2   = (const float*)d_in[16];
  const float* hw   = (const float*)d_in[17];
  const float* hb   = (const float*)d_in[18];
  float* out = (float*)d_out;

  char* ws = (char*)d_ws;
  size_t off = 0;
  auto alloc = [&](size_t n) { void* p = ws + off; off = (off + n + 255) & ~(size_t)255; return p; };

  const long AWs = (long)B_ * 49152;
  const long F1s = (long)B_ * 65536;
  const long F2s = (long)B_ * 65536;

  short* ff1h  = (short*)alloc((size_t)B_ * S_ * 512 * 2);   // aliases xFh
  short* ff1l  = (short*)alloc((size_t)B_ * S_ * 512 * 2);
  short* xFh   = ff1h;    // x planes dead before ff1 written
  short* xFl   = ff1l;
  float* h_f   = (float*)alloc((size_t)B_ * S_ * D_ * 4);
  short* hFh   = (short*)alloc((size_t)B_ * S_ * D_ * 2);
  short* hFl   = (short*)alloc((size_t)B_ * S_ * D_ * 2);
  short* hidFh = (short*)alloc((size_t)L_ * 32 * HID_ * 2);
  short* hidFl = (short*)alloc((size_t)L_ * 32 * HID_ * 2);
  short* awFh  = (short*)alloc((size_t)L_ * AWs * 2);
  short* awFl  = (short*)alloc((size_t)L_ * AWs * 2);
  short* f1wFh = (short*)alloc((size_t)L_ * F1s * 2);
  short* f1wFl = (short*)alloc((size_t)L_ * F1s * 2);
  short* f2wFh = (short*)alloc((size_t)L_ * F2s * 2);
  short* f2wFl = (short*)alloc((size_t)L_ * F2s * 2);
  float* abF   = (float*)alloc((size_t)L_ * B_ * 384 * 4);
  float* f1bF  = (float*)alloc((size_t)L_ * B_ * 512 * 4);
  float* f2bF  = (float*)alloc((size_t)L_ * B_ * 128 * 4);
  short* qkFh  = (short*)alloc((size_t)B_ * S_ * 256 * 2);
  short* qkFl  = (short*)alloc((size_t)B_ * S_ * 256 * 2);
  short* vtFh  = (short*)alloc((size_t)B_ * H_ * 32 * S_ * 2);
  short* vtFl  = (short*)alloc((size_t)B_ * H_ * 32 * S_ * 2);
  short* cxFh  = (short*)alloc((size_t)B_ * S_ * D_ * 2);
  short* cxFl  = (short*)alloc((size_t)B_ * S_ * D_ * 2);
  short* ipwFh = (short*)alloc((size_t)D_ * INDIM * 2);
  short* ipwFl = (short*)alloc((size_t)D_ * INDIM * 2);
  short* opwFh = (short*)alloc((size_t)L_ * D_ * D_ * 2);
  short* opwFl = (short*)alloc((size_t)L_ * D_ * D_ * 2);

  // prep: all conversions + hypernet stage 1, one dispatch
  k_prep<<<2144, 256, 0, stream>>>(x, ipw, opw, xFh, xFl, ipwFh, ipwFl,
                                   opwFh, opwFl, cvec, h1w, h1b, hidFh, hidFl);

  // flat (both layers) + in_proj merged (in_proj blocks first)
  k_flat_ip<<<256 + 2 * 2832, 256, 0, stream>>>(
      hidFh, hidFl, h2w, h2b, awFh, awFl, f1wFh, f1wFl, f2wFh, f2wFl,
      abF, f1bF, f2bF,
      xFh, xFl, ipwFh, ipwFl, ipb, pe, h_f, hFh, hFl);

  constexpr size_t TILE_LDS = 64 * TP * 4;   // 33792

  // ===== layer 0 (full) =====
  {
    int l = 0;
    k_gemm<D_, 5, false><<<dim3(8, 3, B_), 256, TILE_LDS, stream>>>(
        hFh, hFl, (long)S_ * D_, awFh + l * AWs, awFl + l * AWs, 49152,
        abF + l * B_ * 384, 384,
        qkFh, qkFl, vtFh, vtFl, 256, nullptr, nullptr, nullptr, 0, 0, 0);
    k_attn<<<dim3(S_ / 16, H_, B_), 128, 0, stream>>>(qkFh, qkFl, vtFh, vtFl, cxFh, cxFl, 0);
    k_gemm<D_, 4, false><<<dim3(8, 1, B_), 256, TILE_LDS, stream>>>(
        cxFh, cxFl, (long)S_ * D_, opwFh + l * 16384, opwFl + l * 16384, 0,
        opb + l * D_, 0, h_f, hFh, hFl, nullptr, 128,
        ln1g + l * D_, ln1b + l * D_, a1 + l, 0, 0, 0);
    k_gemm<D_, 0, true><<<dim3(8, 4, B_), 256, TILE_LDS, stream>>>(
        hFh, hFl, (long)S_ * D_, f1wFh + l * F1s, f1wFl + l * F1s, 65536,
        f1bF + l * B_ * 512, 512,
        ff1h, ff1l, nullptr, nullptr, 512, nullptr, nullptr, nullptr, 0, 0, 0);
    k_gemm<512, 4, false><<<dim3(8, 1, B_), 256, TILE_LDS, stream>>>(
        ff1h, ff1l, (long)S_ * 512, f2wFh + l * F2s, f2wFl + l * F2s, 65536,
        f2bF + l * B_ * 128, 128,
        h_f, hFh, hFl, nullptr, 128,
        ln2g + l * D_, ln2b + l * D_, a2 + l, 0, 0, 0);
  }

  // ===== layer 1 (pruned: only row 511 reaches the head) =====
  {
    int l = 1;
    // merged kv(full) + q(last m-tile): mode 1 decode, 17 blocks per batch
    k_gemm<D_, 5, false><<<dim3(17, 1, B_), 256, TILE_LDS, stream>>>(
        hFh, hFl, (long)S_ * D_, awFh + l * AWs, awFl + l * AWs, 49152,
        abF + l * B_ * 384, 384,
        qkFh, qkFl, vtFh, vtFl, 256, nullptr, nullptr, nullptr, 0, 0, 1);
    k_attn<<<dim3(1, H_, B_), 128, 0, stream>>>(qkFh, qkFl, vtFh, vtFl, cxFh, cxFl, 31);
    k_gemm<D_, 4, false><<<dim3(1, 1, B_), 256, TILE_LDS, stream>>>(
        cxFh, cxFl, (long)S_ * D_, opwFh + l * 16384, opwFl + l * 16384, 0,
        opb + l * D_, 0, h_f, hFh, hFl, nullptr, 128,
        ln1g + l * D_, ln1b + l * D_, a1 + l, 7, 0, 0);
    k_gemm<D_, 0, true><<<dim3(1, 4, B_), 256, TILE_LDS, stream>>>(
        hFh, hFl, (long)S_ * D_, f1wFh + l * F1s, f1wFl + l * F1s, 65536,
        f1bF + l * B_ * 512, 512,
        ff1h, ff1l, nullptr, nullptr, 512, nullptr, nullptr, nullptr, 7, 0, 0);
    k_gemm<512, 4, false><<<dim3(1, 1, B_), 256, TILE_LDS, stream>>>(
        ff1h, ff1l, (long)S_ * 512, f2wFh + l * F2s, f2wFl + l * F2s, 65536,
        f2bF + l * B_ * 128, 128,
        h_f, hFh, hFl, nullptr, 128,
        ln2g + l * D_, ln2b + l * D_, a2 + l, 7, 0, 0);
  }
  k_head<<<B_, 64, 0, stream>>>(h_f, hw, hb, out);
}

// Round 11
// 417.068 us; speedup vs baseline: 1.3384x; 1.0554x over previous
//
#include <hip/hip_runtime.h>
#include <hip/hip_bf16.h>

// ---------------- constants ----------------
constexpr int B_    = 32;
constexpr int S_    = 512;
constexpr int INDIM = 256;
constexpr int KCTX  = 128;
constexpr int D_    = 128;
constexpr int H_    = 4;
constexpr int L_    = 2;
constexpr int HID_  = 512;
constexpr int TOTAL_ = 11 * D_ * D_ + 8 * D_;   // 181248
constexpr int OFF_AB  = 3 * D_ * D_;            // 49152
constexpr int OFF_F1W = OFF_AB + 3 * D_;        // 49536
constexpr int OFF_F1B = OFF_F1W + 4 * D_ * D_;  // 115072
constexpr int OFF_F2W = OFF_F1B + 4 * D_;       // 115584
constexpr int OFF_F2B = OFF_F2W + 4 * D_ * D_;  // 181120
constexpr int TP = 132;                          // LDS tile pitch (f32)

typedef __attribute__((ext_vector_type(8))) short short8;
typedef __attribute__((ext_vector_type(4))) short short4v;
typedef __attribute__((ext_vector_type(2))) short short2v;
typedef __attribute__((ext_vector_type(4))) float f32x4;

#define MFMA16 __builtin_amdgcn_mfma_f32_16x16x32_bf16

__device__ __forceinline__ short f2bf(float f) {
  __hip_bfloat16 h = __float2bfloat16(f);
  return __builtin_bit_cast(short, h);
}
__device__ __forceinline__ float bf2f(short s) {
  __hip_bfloat16 h = __builtin_bit_cast(__hip_bfloat16, s);
  return __bfloat162float(h);
}
struct bfpair { short hi, lo; };
__device__ __forceinline__ bfpair split2p(float x) {
  bfpair p;
  p.hi = f2bf(x);
  p.lo = f2bf(x - bf2f(p.hi));
  return p;
}

// ---------------- prep: cvt ipw/opw + hid ----------------
__device__ __forceinline__ void cvt_body(const float* __restrict__ in,
                                         short* __restrict__ oh,
                                         short* __restrict__ ol,
                                         int ktShift, int n8, int t) {
  if (t >= n8) return;
  int kt = 1 << ktShift;
  int row = t >> ktShift;
  int kc = t & (kt - 1);
  const float* p = in + ((long)row << (ktShift + 3)) + kc * 8;
  float4 v0 = *(const float4*)p;
  float4 v1 = *(const float4*)(p + 4);
  short8 h8, l8; bfpair q;
  q = split2p(v0.x); h8[0] = q.hi; l8[0] = q.lo;
  q = split2p(v0.y); h8[1] = q.hi; l8[1] = q.lo;
  q = split2p(v0.z); h8[2] = q.hi; l8[2] = q.lo;
  q = split2p(v0.w); h8[3] = q.hi; l8[3] = q.lo;
  q = split2p(v1.x); h8[4] = q.hi; l8[4] = q.lo;
  q = split2p(v1.y); h8[5] = q.hi; l8[5] = q.lo;
  q = split2p(v1.z); h8[6] = q.hi; l8[6] = q.lo;
  q = split2p(v1.w); h8[7] = q.hi; l8[7] = q.lo;
  long o = ((long)(row >> 4) * kt + kc) * 128 + (row & 15) * 8;
  *(short8*)(oh + o) = h8;
  *(short8*)(ol + o) = l8;
}

__global__ __launch_bounds__(256) void k_prep(
    const float* __restrict__ ipw, const float* __restrict__ opw,
    short* __restrict__ ipwFh, short* __restrict__ ipwFl,
    short* __restrict__ opwFh, short* __restrict__ opwFl,
    const float* __restrict__ cvec, const float* __restrict__ h1w,
    const float* __restrict__ h1b,
    short* __restrict__ hidFh, short* __restrict__ hidFl) {
  int id = blockIdx.x, tid = threadIdx.x;
  if (id < 16) {
    cvt_body(ipw, ipwFh, ipwFl, 5, D_ * INDIM / 8, id * 256 + tid);
  } else if (id < 32) {
    cvt_body(opw, opwFh, opwFl, 4, L_ * D_ * D_ / 8, (id - 16) * 256 + tid);
  } else {
    int hb = id - 32;             // 0..63
    int l = hb >> 5, b = hb & 31;
    __shared__ float cs[KCTX];
    if (tid < KCTX) cs[tid] = cvec[b * KCTX + tid];
    __syncthreads();
    #pragma unroll
    for (int jj = 0; jj < 2; ++jj) {
      int j = tid + jj * 256;
      const float* wr = h1w + (long)(l * HID_ + j) * KCTX;
      float s = h1b[l * HID_ + j];
      #pragma unroll
      for (int c = 0; c < KCTX; c += 4) {
        float4 cv = *(const float4*)(cs + c);
        float4 wv = *(const float4*)(wr + c);
        s += cv.x * wv.x + cv.y * wv.y + cv.z * wv.z + cv.w * wv.w;
      }
      s = fmaxf(s, 0.f);
      bfpair p = split2p(s);
      long o = (long)l * 32 * HID_ + ((long)(b >> 4) * 64 + (j >> 3)) * 128
             + (b & 15) * 8 + (j & 7);
      hidFh[o] = p.hi;
      hidFl[o] = p.lo;
    }
  }
}

// ---------------- k_flat_ip: in_proj (f32 x, LDS-staged) + flat (dbuf LDS) ---
__global__ __launch_bounds__(256) void k_flat_ip(
    const short* __restrict__ hidh, const short* __restrict__ hidl,
    const float* __restrict__ W, const float* __restrict__ bias,
    short* __restrict__ awh, short* __restrict__ awl,
    short* __restrict__ f1h, short* __restrict__ f1l,
    short* __restrict__ f2h, short* __restrict__ f2l,
    float* __restrict__ ab, float* __restrict__ f1b, float* __restrict__ f2b,
    const float* __restrict__ x,
    const short* __restrict__ ipwFh, const short* __restrict__ ipwFl,
    const float* __restrict__ ipb, const float* __restrict__ pe,
    float* __restrict__ h_f, short* __restrict__ hFh, short* __restrict__ hFl) {
  __shared__ short wls[2][2][64 * 64];   // [buf][plane], 32 KB
  const int id = blockIdx.x;
  const int tid = threadIdx.x, wave = tid >> 6, lane = tid & 63;
  const int r = lane & 15, g = lane >> 4;
  const int rr = tid >> 4;            // 0..15
  const int cc = (tid & 15) * 4;      // 0..60

  if (id < 256) {
    // ======== in_proj: h = x @ ipw^T + b + pe, A staged from f32 ========
    const int bx = id >> 5, b = id & 31;
    const float* abase = x + ((long)b * S_ + bx * 64) * INDIM;
    float4 av[2][4];
    #pragma unroll
    for (int rnd = 0; rnd < 4; ++rnd) {
      av[0][rnd] = *(const float4*)(abase + (long)(rnd * 16 + rr) * INDIM + cc);
      av[1][rnd] = *(const float4*)(abase + (long)(rnd * 16 + rr) * INDIM + 64 + cc);
    }
    const int n0 = (wave >> 1) * 64;
    const short* pWh = ipwFh + (n0 >> 4) * 4096 + g * 128 + r * 8;
    const short* pWl = ipwFl + (n0 >> 4) * 4096 + g * 128 + r * 8;
    f32x4 acc[2][4] = {{{0,0,0,0},{0,0,0,0},{0,0,0,0},{0,0,0,0}},
                       {{0,0,0,0},{0,0,0,0},{0,0,0,0},{0,0,0,0}}};
    for (int i = 0; i < 4; ++i) {
      int c0 = i * 64, cur = i & 1;
      #pragma unroll
      for (int rnd = 0; rnd < 4; ++rnd) {
        int row = rnd * 16 + rr;
        short4v h4, l4; bfpair q;
        q = split2p(av[cur][rnd].x); h4[0] = q.hi; l4[0] = q.lo;
        q = split2p(av[cur][rnd].y); h4[1] = q.hi; l4[1] = q.lo;
        q = split2p(av[cur][rnd].z); h4[2] = q.hi; l4[2] = q.lo;
        q = split2p(av[cur][rnd].w); h4[3] = q.hi; l4[3] = q.lo;
        int sb = row * 128 + ((cc * 2) ^ ((row & 7) << 4));
        *(short4v*)((char*)&wls[cur][0][0] + sb) = h4;
        *(short4v*)((char*)&wls[cur][1][0] + sb) = l4;
      }
      if (i + 2 < 4) {
        #pragma unroll
        for (int rnd = 0; rnd < 4; ++rnd)
          av[cur][rnd] = *(const float4*)(abase + (long)(rnd * 16 + rr) * INDIM + (c0 + 128) + cc);
      }
      __syncthreads();
      #pragma unroll
      for (int kk = 0; kk < 2; ++kk) {
        long wo = (long)(c0 * 16) + kk * 512;
        short8 ah[2], al[2];
        #pragma unroll
        for (int ms = 0; ms < 2; ++ms) {
          int arow = (wave & 1) * 32 + ms * 16 + r;
          int abyte = arow * 128 + ((kk * 64 + g * 16) ^ ((r & 7) << 4));
          ah[ms] = *(const short8*)((char*)&wls[cur][0][0] + abyte);
          al[ms] = *(const short8*)((char*)&wls[cur][1][0] + abyte);
        }
        #pragma unroll
        for (int ns = 0; ns < 4; ++ns) {
          short8 wh = *(const short8*)(pWh + ns * 4096 + wo);
          short8 wl = *(const short8*)(pWl + ns * 4096 + wo);
          #pragma unroll
          for (int ms = 0; ms < 2; ++ms) {
            acc[ms][ns] = MFMA16(ah[ms], wl, acc[ms][ns], 0, 0, 0);
            acc[ms][ns] = MFMA16(al[ms], wh, acc[ms][ns], 0, 0, 0);
            acc[ms][ns] = MFMA16(ah[ms], wh, acc[ms][ns], 0, 0, 0);
          }
        }
      }
      __syncthreads();
    }
    #pragma unroll
    for (int ms = 0; ms < 2; ++ms) {
      #pragma unroll
      for (int ns = 0; ns < 4; ++ns) {
        int ccol = n0 + ns * 16 + r;
        float bv = ipb[ccol];
        #pragma unroll
        for (int reg = 0; reg < 4; ++reg) {
          int crow = bx * 64 + (wave & 1) * 32 + ms * 16 + g * 4 + reg;
          float v = acc[ms][ns][reg] + bv + pe[crow * D_ + ccol];
          h_f[((long)b * S_ + crow) * D_ + ccol] = v;
          long o = (long)b * 65536 + (long)(crow >> 4) * 2048
                 + (ccol >> 3) * 128 + (crow & 15) * 8 + (ccol & 7);
          bfpair sp = split2p(v);
          hFh[o] = sp.hi;
          hFl[o] = sp.lo;
        }
      }
    }
    return;
  }

  // ======== flat (both layers), double-buffered LDS ========
  const int fid = id - 256;
  const int l = fid / 2832;
  const int bxf = fid % 2832;
  hidh += (long)l * 32 * HID_;
  hidl += (long)l * 32 * HID_;
  W    += (long)l * TOTAL_ * HID_;
  bias += (long)l * TOTAL_;
  awh  += (long)l * B_ * 49152;  awl += (long)l * B_ * 49152;
  f1h  += (long)l * B_ * 65536;  f1l += (long)l * B_ * 65536;
  f2h  += (long)l * B_ * 65536;  f2l += (long)l * B_ * 65536;
  ab   += l * B_ * 384;  f1b += l * B_ * 512;  f2b += l * B_ * 128;
  const int nb0 = bxf * 64;
  const float* wbase = W + (long)nb0 * HID_;
  float4 wv[2][4];
  #pragma unroll
  for (int rnd = 0; rnd < 4; ++rnd) {
    wv[0][rnd] = *(const float4*)(wbase + (long)(rnd * 16 + rr) * HID_ + cc);
    wv[1][rnd] = *(const float4*)(wbase + (long)(rnd * 16 + rr) * HID_ + 64 + cc);
  }
  const short* pAh = hidh + g * 128 + r * 8;
  const short* pAl = hidl + g * 128 + r * 8;
  f32x4 acc0 = {0, 0, 0, 0}, acc1 = {0, 0, 0, 0};
  for (int i = 0; i < 8; ++i) {
    int c0 = i * 64, cur = i & 1;
    #pragma unroll
    for (int rnd = 0; rnd < 4; ++rnd) {
      int row = rnd * 16 + rr;
      short4v h4, l4; bfpair q;
      q = split2p(wv[cur][rnd].x); h4[0] = q.hi; l4[0] = q.lo;
      q = split2p(wv[cur][rnd].y); h4[1] = q.hi; l4[1] = q.lo;
      q = split2p(wv[cur][rnd].z); h4[2] = q.hi; l4[2] = q.lo;
      q = split2p(wv[cur][rnd].w); h4[3] = q.hi; l4[3] = q.lo;
      int sb = row * 128 + ((cc * 2) ^ ((row & 7) << 4));
      *(short4v*)((char*)&wls[cur][0][0] + sb) = h4;
      *(short4v*)((char*)&wls[cur][1][0] + sb) = l4;
    }
    if (i + 2 < 8) {
      #pragma unroll
      for (int rnd = 0; rnd < 4; ++rnd)
        wv[cur][rnd] = *(const float4*)(wbase + (long)(rnd * 16 + rr) * HID_ + (c0 + 128) + cc);
    }
    __syncthreads();
    #pragma unroll
    for (int kk = 0; kk < 2; ++kk) {
      long ao = (long)(c0 * 16) + kk * 512;
      short8 ah0 = *(const short8*)(pAh + ao);
      short8 ah1 = *(const short8*)(pAh + 8192 + ao);
      short8 al0 = *(const short8*)(pAl + ao);
      short8 al1 = *(const short8*)(pAl + 8192 + ao);
      int wrow = wave * 16 + r;
      int wb = wrow * 128 + ((kk * 64 + g * 16) ^ ((r & 7) << 4));
      short8 wh = *(const short8*)((char*)&wls[cur][0][0] + wb);
      short8 wl = *(const short8*)((char*)&wls[cur][1][0] + wb);
      acc0 = MFMA16(ah0, wl, acc0, 0, 0, 0);
      acc0 = MFMA16(al0, wh, acc0, 0, 0, 0);
      acc0 = MFMA16(ah0, wh, acc0, 0, 0, 0);
      acc1 = MFMA16(ah1, wl, acc1, 0, 0, 0);
      acc1 = MFMA16(al1, wh, acc1, 0, 0, 0);
      acc1 = MFMA16(ah1, wh, acc1, 0, 0, 0);
    }
    __syncthreads();
  }
  // vectorized epilogue via LDS
  constexpr int TPF = 68;
  float* tile = (float*)&wls[0][0][0];
  {
    float bv = bias[nb0 + wave * 16 + r];
    int col = wave * 16 + r;
    #pragma unroll
    for (int reg = 0; reg < 4; ++reg) {
      tile[(g * 4 + reg) * TPF + col]      = acc0[reg] + bv;
      tile[(g * 4 + reg + 16) * TPF + col] = acc1[reg] + bv;
    }
  }
  __syncthreads();
  {
    int b  = tid >> 3;
    int cg = tid & 7;
    int t0 = nb0 + cg * 8;
    float v[8];
    #pragma unroll
    for (int j = 0; j < 8; ++j) v[j] = tile[b * TPF + cg * 8 + j];
    if (t0 < OFF_AB) {
      int e = t0 >> 7, d = t0 & 127;
      long a = (long)b * 49152 + ((long)(e >> 4) * 16 + (d >> 3)) * 128 + (e & 15) * 8;
      short8 h8, l8; bfpair q;
      #pragma unroll
      for (int j = 0; j < 8; ++j) { q = split2p(v[j]); h8[j] = q.hi; l8[j] = q.lo; }
      *(short8*)(awh + a) = h8;
      *(short8*)(awl + a) = l8;
    } else if (t0 < OFF_F1W) {
      float* dst = ab + b * 384 + (t0 - OFF_AB);
      float4 x0 = {v[0], v[1], v[2], v[3]}, x1 = {v[4], v[5], v[6], v[7]};
      *(float4*)dst = x0; *(float4*)(dst + 4) = x1;
    } else if (t0 < OFF_F1B) {
      int i = t0 - OFF_F1W; int f = i >> 7, d = i & 127;
      long a = (long)b * 65536 + ((long)(f >> 4) * 16 + (d >> 3)) * 128 + (f & 15) * 8;
      short8 h8, l8; bfpair q;
      #pragma unroll
      for (int j = 0; j < 8; ++j) { q = split2p(v[j]); h8[j] = q.hi; l8[j] = q.lo; }
      *(short8*)(f1h + a) = h8;
      *(short8*)(f1l + a) = l8;
    } else if (t0 < OFF_F2W) {
      float* dst = f1b + b * 512 + (t0 - OFF_F1B);
      float4 x0 = {v[0], v[1], v[2], v[3]}, x1 = {v[4], v[5], v[6], v[7]};
      *(float4*)dst = x0; *(float4*)(dst + 4) = x1;
    } else if (t0 < OFF_F2B) {
      int i = t0 - OFF_F2W; int dd = i >> 9, f = i & 511;
      long a = (long)b * 65536 + ((long)(dd >> 4) * 64 + (f >> 3)) * 128 + (dd & 15) * 8;
      short8 h8, l8; bfpair q;
      #pragma unroll
      for (int j = 0; j < 8; ++j) { q = split2p(v[j]); h8[j] = q.hi; l8[j] = q.lo; }
      *(short8*)(f2h + a) = h8;
      *(short8*)(f2l + a) = l8;
    } else {
      float* dst = f2b + b * 128 + (t0 - OFF_F2B);
      float4 x0 = {v[0], v[1], v[2], v[3]}, x1 = {v[4], v[5], v[6], v[7]};
      *(float4*)dst = x0; *(float4*)(dst + 4) = x1;
    }
  }
}

// ---------------- generic batched split-MFMA GEMM, FT operands ----------------
template <int K, int EPI, bool RELU>
__global__ __launch_bounds__(256) void k_gemm(
    const short* __restrict__ Ah, const short* __restrict__ Al, long sA,
    const short* __restrict__ Wh, const short* __restrict__ Wl, long sW,
    const float* __restrict__ biasP, long sB,
    void* __restrict__ p0, void* __restrict__ p1,
    void* __restrict__ p2, void* __restrict__ p3,
    int N,
    const float* __restrict__ lng, const float* __restrict__ lnb,
    const float* __restrict__ lnal, int mOff, int nOff, int mode) {
  extern __shared__ char smem_dyn[];
  const int tid = threadIdx.x, wave = tid >> 6, lane = tid & 63;
  const int r = lane & 15, g = lane >> 4;
  const int b = blockIdx.z;
  int bx, by;
  if (mode == 1) {
    int xx = blockIdx.x;
    if (xx < 16) { bx = xx >> 1; by = 1 + (xx & 1); }
    else         { bx = 7; by = 0; }
  } else {
    bx = blockIdx.x + mOff; by = blockIdx.y + nOff;
  }
  const int m0 = bx * 64 + (wave & 1) * 32;
  const int n0 = by * 128 + (wave >> 1) * 64;
  const long KT = (long)K * 16;
  const short* pAh = Ah + (long)b * sA + (m0 >> 4) * KT + g * 128 + r * 8;
  const short* pAl = Al + (long)b * sA + (m0 >> 4) * KT + g * 128 + r * 8;
  const short* pWh = Wh + (long)b * sW + (n0 >> 4) * KT + g * 128 + r * 8;
  const short* pWl = Wl + (long)b * sW + (n0 >> 4) * KT + g * 128 + r * 8;
  f32x4 acc[2][4] = {{{0,0,0,0},{0,0,0,0},{0,0,0,0},{0,0,0,0}},
                     {{0,0,0,0},{0,0,0,0},{0,0,0,0},{0,0,0,0}}};
  for (int kk = 0; kk < K / 32; ++kk) {
    long ko = (long)kk * 512;
    short8 a0h = *(const short8*)(pAh + ko);
    short8 a1h = *(const short8*)(pAh + KT + ko);
    short8 a0l = *(const short8*)(pAl + ko);
    short8 a1l = *(const short8*)(pAl + KT + ko);
    #pragma unroll
    for (int ns = 0; ns < 4; ++ns) {
      short8 wh = *(const short8*)(pWh + ns * KT + ko);
      short8 wl = *(const short8*)(pWl + ns * KT + ko);
      acc[0][ns] = MFMA16(a0h, wl, acc[0][ns], 0, 0, 0);
      acc[0][ns] = MFMA16(a0l, wh, acc[0][ns], 0, 0, 0);
      acc[0][ns] = MFMA16(a0h, wh, acc[0][ns], 0, 0, 0);
      acc[1][ns] = MFMA16(a1h, wl, acc[1][ns], 0, 0, 0);
      acc[1][ns] = MFMA16(a1l, wh, acc[1][ns], 0, 0, 0);
      acc[1][ns] = MFMA16(a1h, wh, acc[1][ns], 0, 0, 0);
    }
  }

  if constexpr (EPI == 5) {
    if (by == 2) {
      #pragma unroll
      for (int ms = 0; ms < 2; ++ms) {
        int crow0 = m0 + ms * 16 + g * 4;
        #pragma unroll
        for (int ns = 0; ns < 4; ++ns) {
          int ccol = n0 + ns * 16 + r;
          float bv = biasP[(long)b * sB + ccol];
          int c2 = ccol - 256, hd = c2 >> 5, dd = c2 & 31;
          short4v h4, l4; bfpair q;
          #pragma unroll
          for (int reg = 0; reg < 4; ++reg) {
            float v = acc[ms][ns][reg] + bv;
            q = split2p(v); h4[reg] = q.hi; l4[reg] = q.lo;
          }
          long o = (long)(b * 4 + hd) * 16384 + (dd >> 4) * 8192
                 + (crow0 >> 3) * 128 + (dd & 15) * 8 + (crow0 & 7);
          *(short4v*)((short*)p2 + o) = h4;
          *(short4v*)((short*)p3 + o) = l4;
        }
      }
      return;
    }
  }

  float* tile = (float*)smem_dyn;
  #pragma unroll
  for (int ms = 0; ms < 2; ++ms) {
    #pragma unroll
    for (int ns = 0; ns < 4; ++ns) {
      int ccol = n0 + ns * 16 + r;
      float bv = biasP[(long)b * sB + ccol];
      #pragma unroll
      for (int reg = 0; reg < 4; ++reg) {
        float v = acc[ms][ns][reg] + bv;
        if constexpr (RELU) v = fmaxf(v, 0.f);
        int trow2 = (wave & 1) * 32 + ms * 16 + g * 4 + reg;
        int tcol = (wave >> 1) * 64 + ns * 16 + r;
        tile[trow2 * TP + tcol] = v;
      }
    }
  }
  __syncthreads();

  if constexpr (EPI == 0 || EPI == 5) {
    int row = tid >> 2, cg = tid & 3;
    int crow = bx * 64 + row;
    long rowbase = (long)b * 512 * N + (long)(crow >> 4) * (16 * (long)N) + (crow & 15) * 8;
    #pragma unroll
    for (int j4 = 0; j4 < 4; ++j4) {
      int tcol = j4 * 32 + cg * 8;
      float4 aa = *(const float4*)&tile[row * TP + tcol];
      float4 bb = *(const float4*)&tile[row * TP + tcol + 4];
      short8 h8, l8; bfpair q;
      q = split2p(aa.x); h8[0] = q.hi; l8[0] = q.lo;
      q = split2p(aa.y); h8[1] = q.hi; l8[1] = q.lo;
      q = split2p(aa.z); h8[2] = q.hi; l8[2] = q.lo;
      q = split2p(aa.w); h8[3] = q.hi; l8[3] = q.lo;
      q = split2p(bb.x); h8[4] = q.hi; l8[4] = q.lo;
      q = split2p(bb.y); h8[5] = q.hi; l8[5] = q.lo;
      q = split2p(bb.z); h8[6] = q.hi; l8[6] = q.lo;
      q = split2p(bb.w); h8[7] = q.hi; l8[7] = q.lo;
      int ccol = by * 128 + tcol;
      long o = rowbase + (long)(ccol >> 3) * 128;
      *(short8*)((short*)p0 + o) = h8;
      *(short8*)((short*)p1 + o) = l8;
    }
  } else if constexpr (EPI == 4) {
    int row = tid >> 2, q = tid & 3;
    int brow = bx * 64 + row;
    float a = lnal[0];
    float* hf = (float*)p0;
    float* hrow = hf + ((long)b * S_ + brow) * D_ + q * 32;
    float tv[32];
    float s = 0.f, ss = 0.f;
    #pragma unroll
    for (int i = 0; i < 32; i += 4) {
      float4 hv = *(const float4*)(hrow + i);
      float4 yv = *(const float4*)&tile[row * TP + q * 32 + i];
      float t0 = hv.x + a * yv.x, t1 = hv.y + a * yv.y;
      float t2 = hv.z + a * yv.z, t3 = hv.w + a * yv.w;
      tv[i] = t0; tv[i+1] = t1; tv[i+2] = t2; tv[i+3] = t3;
      s += t0 + t1 + t2 + t3;
      ss += t0*t0 + t1*t1 + t2*t2 + t3*t3;
    }
    s  += __shfl_xor(s, 1);  s  += __shfl_xor(s, 2);
    ss += __shfl_xor(ss, 1); ss += __shfl_xor(ss, 2);
    float mu = s * (1.f / 128.f);
    float varv = ss * (1.f / 128.f) - mu * mu;
    float inv = rsqrtf(varv + 1e-5f);
    short* ph = (short*)p1; short* pl = (short*)p2;
    long fb = (long)b * 65536 + (long)(brow >> 4) * 2048 + (brow & 15) * 8;
    #pragma unroll
    for (int j = 0; j < 4; ++j) {
      short8 hv8, lv8;
      #pragma unroll
      for (int e = 0; e < 8; e += 4) {
        int i = j * 8 + e;
        int c = q * 32 + i;
        float4 gv = *(const float4*)(lng + c);
        float4 bb = *(const float4*)(lnb + c);
        float4 o4;
        o4.x = (tv[i]   - mu) * inv * gv.x + bb.x;
        o4.y = (tv[i+1] - mu) * inv * gv.y + bb.y;
        o4.z = (tv[i+2] - mu) * inv * gv.z + bb.z;
        o4.w = (tv[i+3] - mu) * inv * gv.w + bb.w;
        *(float4*)(hrow + i) = o4;
        bfpair q0 = split2p(o4.x); hv8[e]   = q0.hi; lv8[e]   = q0.lo;
        bfpair q1 = split2p(o4.y); hv8[e+1] = q1.hi; lv8[e+1] = q1.lo;
        bfpair q2 = split2p(o4.z); hv8[e+2] = q2.hi; lv8[e+2] = q2.lo;
        bfpair q3 = split2p(o4.w); hv8[e+3] = q3.hi; lv8[e+3] = q3.lo;
      }
      long o = fb + (q * 4 + j) * 128;
      *(short8*)(ph + o) = hv8;
      *(short8*)(pl + o) = lv8;
    }
  }
}

// ---------------- attention: 16 q-rows/block, 2 cooperating waves ------------
__global__ __launch_bounds__(128) void k_attn(const short* __restrict__ qkh,
                                              const short* __restrict__ qkl,
                                              const short* __restrict__ vth,
                                              const short* __restrict__ vtl,
                                              short* __restrict__ ch,
                                              short* __restrict__ cl,
                                              int mOff) {
  __shared__ __align__(16) float scr[16][516];   // 33 KB
  __shared__ __align__(16) float obuf[16][34];   // 2.2 KB
  const int tid = threadIdx.x, wave = tid >> 6, lane = tid & 63;
  const int r = lane & 15, g = lane >> 4;
  const int b = blockIdx.z, hh = blockIdx.y;
  const int m0 = (blockIdx.x + mOff) * 16;
  const long qb = (long)b * 131072;
  const long qoff = qb + (long)(m0 >> 4) * 4096 + (hh * 4 + g) * 128 + r * 8;
  short8 qh = *(const short8*)(qkh + qoff);
  short8 ql = *(const short8*)(qkl + qoff);
  const float sc = 0.17677669529663687f;  // 1/sqrt(32)
  for (int n0 = wave * 256; n0 < wave * 256 + 256; n0 += 16) {
    long koff = qb + (long)(n0 >> 4) * 4096 + (16 + hh * 4 + g) * 128 + r * 8;
    short8 kh = *(const short8*)(qkh + koff);
    short8 kl = *(const short8*)(qkl + koff);
    f32x4 s = {0, 0, 0, 0};
    s = MFMA16(qh, kl, s, 0, 0, 0);
    s = MFMA16(ql, kh, s, 0, 0, 0);
    s = MFMA16(qh, kh, s, 0, 0, 0);
    #pragma unroll
    for (int reg = 0; reg < 4; ++reg)
      scr[g * 4 + reg][n0 + r] = s[reg] * sc;
  }
  __syncthreads();
  for (int row = wave * 8; row < wave * 8 + 8; ++row) {
    float v[8];
    #pragma unroll
    for (int i = 0; i < 8; ++i) v[i] = scr[row][lane + i * 64];
    float m = v[0];
    #pragma unroll
    for (int i = 1; i < 8; ++i) m = fmaxf(m, v[i]);
    #pragma unroll
    for (int o = 32; o > 0; o >>= 1) m = fmaxf(m, __shfl_xor(m, o));
    float ssum = 0.f;
    #pragma unroll
    for (int i = 0; i < 8; ++i) { v[i] = __expf(v[i] - m); ssum += v[i]; }
    #pragma unroll
    for (int o = 32; o > 0; o >>= 1) ssum += __shfl_xor(ssum, o);
    float inv = 1.f / ssum;
    #pragma unroll
    for (int i = 0; i < 8; ++i) scr[row][lane + i * 64] = v[i] * inv;
  }
  __syncthreads();
  f32x4 o0 = {0, 0, 0, 0}, o1 = {0, 0, 0, 0};
  const long vb = (long)(b * 4 + hh) * 16384;
  for (int kt = wave * 8; kt < wave * 8 + 8; ++kt) {
    float4 pv0 = *(const float4*)&scr[r][kt * 32 + g * 8];
    float4 pv1 = *(const float4*)&scr[r][kt * 32 + g * 8 + 4];
    short8 pah, pal;
    bfpair p;
    p = split2p(pv0.x); pah[0] = p.hi; pal[0] = p.lo;
    p = split2p(pv0.y); pah[1] = p.hi; pal[1] = p.lo;
    p = split2p(pv0.z); pah[2] = p.hi; pal[2] = p.lo;
    p = split2p(pv0.w); pah[3] = p.hi; pal[3] = p.lo;
    p = split2p(pv1.x); pah[4] = p.hi; pal[4] = p.lo;
    p = split2p(pv1.y); pah[5] = p.hi; pal[5] = p.lo;
    p = split2p(pv1.z); pah[6] = p.hi; pal[6] = p.lo;
    p = split2p(pv1.w); pah[7] = p.hi; pal[7] = p.lo;
    long vo = vb + (long)(kt * 4 + g) * 128 + r * 8;
    short8 vh0 = *(const short8*)(vth + vo);
    short8 vh1 = *(const short8*)(vth + vo + 8192);
    short8 vl0 = *(const short8*)(vtl + vo);
    short8 vl1 = *(const short8*)(vtl + vo + 8192);
    o0 = MFMA16(pah, vl0, o0, 0, 0, 0);
    o0 = MFMA16(pal, vh0, o0, 0, 0, 0);
    o0 = MFMA16(pah, vh0, o0, 0, 0, 0);
    o1 = MFMA16(pah, vl1, o1, 0, 0, 0);
    o1 = MFMA16(pal, vh1, o1, 0, 0, 0);
    o1 = MFMA16(pah, vh1, o1, 0, 0, 0);
  }
  if (wave == 1) {
    #pragma unroll
    for (int reg = 0; reg < 4; ++reg) {
      obuf[g * 4 + reg][r] = o0[reg];
      obuf[g * 4 + reg][17 + r] = o1[reg];
    }
  }
  __syncthreads();
  if (wave == 0) {
    #pragma unroll
    for (int reg = 0; reg < 4; ++reg) {
      float a0 = o0[reg] + obuf[g * 4 + reg][r];
      float a1 = o1[reg] + obuf[g * 4 + reg][17 + r];
      int srow = m0 + g * 4 + reg;
      int col0 = hh * 32 + r;
      long o = (long)b * 65536 + (long)(srow >> 4) * 2048
             + (col0 >> 3) * 128 + (srow & 15) * 8 + (col0 & 7);
      bfpair sp0 = split2p(a0);
      ch[o] = sp0.hi; cl[o] = sp0.lo;
      long o2 = o + 2 * 128;
      bfpair sp1 = split2p(a1);
      ch[o2] = sp1.hi; cl[o2] = sp1.lo;
    }
  }
}

// ---------------- head ----------------
__global__ __launch_bounds__(64) void k_head(const float* __restrict__ h,
                                             const float* __restrict__ hw,
                                             const float* __restrict__ hb,
                                             float* __restrict__ out) {
  int b = blockIdx.x, lane = threadIdx.x;
  const float* hr = h + ((long)b * S_ + (S_ - 1)) * D_;
  float v = hr[lane] * hw[lane] + hr[lane + 64] * hw[lane + 64];
  #pragma unroll
  for (int o = 32; o > 0; o >>= 1) v += __shfl_xor(v, o);
  if (lane == 0) out[b] = v + hb[0];
}

// ---------------- host ----------------
extern "C" void kernel_launch(void* const* d_in, const int* in_sizes, int n_in,
                              void* d_out, int out_size, void* d_ws, size_t ws_size,
                              hipStream_t stream) {
  const float* x    = (const float*)d_in[0];
  const float* cvec = (const float*)d_in[1];
  const float* ipw  = (const float*)d_in[2];
  const float* ipb  = (const float*)d_in[3];
  const float* pe   = (const float*)d_in[4];
  const float* h1w  = (const float*)d_in[5];
  const float* h1b  = (const float*)d_in[6];
  const float* h2w  = (const float*)d_in[7];
  const float* h2b  = (const float*)d_in[8];
  const float* opw  = (const float*)d_in[9];
  const float* opb  = (const float*)d_in[10];
  const float* ln1g = (const float*)d_in[11];
  const float* ln1b = (const float*)d_in[12];
  const float* ln2g = (const float*)d_in[13];
  const float* ln2b = (const float*)d_in[14];
  const float* a1   = (const float*)d_in[15];
  const float* a2   = (const float*)d_in[16];
  const float* hw   = (const float*)d_in[17];
  const float* hb   = (const float*)d_in[18];
  float* out = (float*)d_out;

  char* ws = (char*)d_ws;
  size_t off = 0;
  auto alloc = [&](size_t n) { void* p = ws + off; off = (off + n + 255) & ~(size_t)255; return p; };

  const long AWs = (long)B_ * 49152;
  const long F1s = (long)B_ * 65536;
  const long F2s = (long)B_ * 65536;

  short* ff1h  = (short*)alloc((size_t)B_ * S_ * 512 * 2);
  short* ff1l  = (short*)alloc((size_t)B_ * S_ * 512 * 2);
  float* h_f   = (float*)alloc((size_t)B_ * S_ * D_ * 4);
  short* hFh   = (short*)alloc((size_t)B_ * S_ * D_ * 2);
  short* hFl   = (short*)alloc((size_t)B_ * S_ * D_ * 2);
  short* hidFh = (short*)alloc((size_t)L_ * 32 * HID_ * 2);
  short* hidFl = (short*)alloc((size_t)L_ * 32 * HID_ * 2);
  short* awFh  = (short*)alloc((size_t)L_ * AWs * 2);
  short* awFl  = (short*)alloc((size_t)L_ * AWs * 2);
  short* f1wFh = (short*)alloc((size_t)L_ * F1s * 2);
  short* f1wFl = (short*)alloc((size_t)L_ * F1s * 2);
  short* f2wFh = (short*)alloc((size_t)L_ * F2s * 2);
  short* f2wFl = (short*)alloc((size_t)L_ * F2s * 2);
  float* abF   = (float*)alloc((size_t)L_ * B_ * 384 * 4);
  float* f1bF  = (float*)alloc((size_t)L_ * B_ * 512 * 4);
  float* f2bF  = (float*)alloc((size_t)L_ * B_ * 128 * 4);
  short* qkFh  = (short*)alloc((size_t)B_ * S_ * 256 * 2);
  short* qkFl  = (short*)alloc((size_t)B_ * S_ * 256 * 2);
  short* vtFh  = (short*)alloc((size_t)B_ * H_ * 32 * S_ * 2);
  short* vtFl  = (short*)alloc((size_t)B_ * H_ * 32 * S_ * 2);
  short* cxFh  = (short*)alloc((size_t)B_ * S_ * D_ * 2);
  short* cxFl  = (short*)alloc((size_t)B_ * S_ * D_ * 2);
  short* ipwFh = (short*)alloc((size_t)D_ * INDIM * 2);
  short* ipwFl = (short*)alloc((size_t)D_ * INDIM * 2);
  short* opwFh = (short*)alloc((size_t)L_ * D_ * D_ * 2);
  short* opwFl = (short*)alloc((size_t)L_ * D_ * D_ * 2);

  // prep: weight conversions + hypernet stage 1
  k_prep<<<96, 256, 0, stream>>>(ipw, opw, ipwFh, ipwFl, opwFh, opwFl,
                                 cvec, h1w, h1b, hidFh, hidFl);

  // flat (both layers) + in_proj (direct f32 x) merged
  k_flat_ip<<<256 + 2 * 2832, 256, 0, stream>>>(
      hidFh, hidFl, h2w, h2b, awFh, awFl, f1wFh, f1wFl, f2wFh, f2wFl,
      abF, f1bF, f2bF,
      x, ipwFh, ipwFl, ipb, pe, h_f, hFh, hFl);

  constexpr size_t TILE_LDS = 64 * TP * 4;   // 33792

  // ===== layer 0 (full) =====
  {
    int l = 0;
    k_gemm<D_, 5, false><<<dim3(8, 3, B_), 256, TILE_LDS, stream>>>(
        hFh, hFl, (long)S_ * D_, awFh + l * AWs, awFl + l * AWs, 49152,
        abF + l * B_ * 384, 384,
        qkFh, qkFl, vtFh, vtFl, 256, nullptr, nullptr, nullptr, 0, 0, 0);
    k_attn<<<dim3(S_ / 16, H_, B_), 128, 0, stream>>>(qkFh, qkFl, vtFh, vtFl, cxFh, cxFl, 0);
    k_gemm<D_, 4, false><<<dim3(8, 1, B_), 256, TILE_LDS, stream>>>(
        cxFh, cxFl, (long)S_ * D_, opwFh + l * 16384, opwFl + l * 16384, 0,
        opb + l * D_, 0, h_f, hFh, hFl, nullptr, 128,
        ln1g + l * D_, ln1b + l * D_, a1 + l, 0, 0, 0);
    k_gemm<D_, 0, true><<<dim3(8, 4, B_), 256, TILE_LDS, stream>>>(
        hFh, hFl, (long)S_ * D_, f1wFh + l * F1s, f1wFl + l * F1s, 65536,
        f1bF + l * B_ * 512, 512,
        ff1h, ff1l, nullptr, nullptr, 512, nullptr, nullptr, nullptr, 0, 0, 0);
    k_gemm<512, 4, false><<<dim3(8, 1, B_), 256, TILE_LDS, stream>>>(
        ff1h, ff1l, (long)S_ * 512, f2wFh + l * F2s, f2wFl + l * F2s, 65536,
        f2bF + l * B_ * 128, 128,
        h_f, hFh, hFl, nullptr, 128,
        ln2g + l * D_, ln2b + l * D_, a2 + l, 0, 0, 0);
  }

  // ===== layer 1 (pruned: only row 511 reaches the head) =====
  {
    int l = 1;
    k_gemm<D_, 5, false><<<dim3(17, 1, B_), 256, TILE_LDS, stream>>>(
        hFh, hFl, (long)S_ * D_, awFh + l * AWs, awFl + l * AWs, 49152,
        abF + l * B_ * 384, 384,
        qkFh, qkFl, vtFh, vtFl, 256, nullptr, nullptr, nullptr, 0, 0, 1);
    k_attn<<<dim3(1, H_, B_), 128, 0, stream>>>(qkFh, qkFl, vtFh, vtFl, cxFh, cxFl, 31);
    k_gemm<D_, 4, false><<<dim3(1, 1, B_), 256, TILE_LDS, stream>>>(
        cxFh, cxFl, (long)S_ * D_, opwFh + l * 16384, opwFl + l * 16384, 0,
        opb + l * D_, 0, h_f, hFh, hFl, nullptr, 128,
        ln1g + l * D_, ln1b + l * D_, a1 + l, 7, 0, 0);
    k_gemm<D_, 0, true><<<dim3(1, 4, B_), 256, TILE_LDS, stream>>>(
        hFh, hFl, (long)S_ * D_, f1wFh + l * F1s, f1wFl + l * F1s, 65536,
        f1bF + l * B_ * 512, 512,
        ff1h, ff1l, nullptr, nullptr, 512, nullptr, nullptr, nullptr, 7, 0, 0);
    k_gemm<512, 4, false><<<dim3(1, 1, B_), 256, TILE_LDS, stream>>>(
        ff1h, ff1l, (long)S_ * 512, f2wFh + l * F2s, f2wFl + l * F2s, 65536,
        f2bF + l * B_ * 128, 128,
        h_f, hFh, hFl, nullptr, 128,
        ln2g + l * D_, ln2b + l * D_, a2 + l, 7, 0, 0);
  }
  k_head<<<B_, 64, 0, stream>>>(h_f, hw, hb, out);
}